// Round 8
// baseline (637.104 us; speedup 1.0000x reference)
//
#include <hip/hip_runtime.h>
#include <hip/hip_bf16.h>
#include <math.h>

#define EMB 768
#define DFF 3072
#define HEADS 12
#define HD 64
#define LSEQ 1024
#define BATCH 16
#define BL (BATCH * LSEQ)   // 16384 rows
#define QKVD 2304           // fused q|k|v column dim
#define QSCALE 0.1803368801111204f  // (1/sqrt(64)) * log2(e)

typedef __attribute__((ext_vector_type(8))) short short8;
typedef __attribute__((ext_vector_type(4))) float floatx4;
typedef unsigned short u16;

__device__ __forceinline__ u16 f2bf(float f) {
  union { float f; unsigned u; } c; c.f = f;
  unsigned u = c.u;
  u += 0x7fffu + ((u >> 16) & 1u);   // round-to-nearest-even
  return (u16)(u >> 16);
}
__device__ __forceinline__ u16 f2bf_trunc(float f) {  // cheap: 1 op, ~0.4% err
  union { float f; unsigned u; } c; c.f = f;
  return (u16)(c.u >> 16);
}
__device__ __forceinline__ float fast_exp2(float x) {
#if __has_builtin(__builtin_amdgcn_exp2f)
  return __builtin_amdgcn_exp2f(x);
#else
  return exp2f(x);
#endif
}
__device__ __forceinline__ float fast_rcp(float x) {
#if __has_builtin(__builtin_amdgcn_rcpf)
  return __builtin_amdgcn_rcpf(x);
#else
  return 1.0f / x;
#endif
}
// gelu exact-erf replacement: tanh form via exp2; |err| <~1e-3, clamped safe
__device__ __forceinline__ float gelu_fast(float x) {
  float x2 = x * x;
  float u = x * fmaf(0.10294540f, x2, 2.30211423f);  // = 2*log2e*0.7978846*(x+0.044715x^3)
  u = fminf(fmaxf(u, -30.f), 30.f);
  float t = fast_exp2(u);
  return x * t * fast_rcp(t + 1.0f);                  // x * sigmoid(2v)
}
// async global->LDS, 16B per lane; lds dest = wave-uniform base + lane*16
__device__ __forceinline__ void async16(const u16* g, u16* l) {
  __builtin_amdgcn_global_load_lds(
      (const __attribute__((address_space(1))) unsigned int*)g,
      (__attribute__((address_space(3))) unsigned int*)l, 16, 0, 0);
}
__device__ __forceinline__ short8 load16(const u16* p) {
  return *reinterpret_cast<const short8*>(p);
}

// ---------------- LayerNorm: fp32 in -> bf16 out (one wave per row) ----------
__global__ __launch_bounds__(256) void ln_kernel(const float* __restrict__ x,
                                                 const float* __restrict__ g,
                                                 const float* __restrict__ b,
                                                 u16* __restrict__ out) {
  int row = blockIdx.x * 4 + (threadIdx.x >> 6);
  int lane = threadIdx.x & 63;
  const float* xr = x + (size_t)row * EMB;
  float v[12];
#pragma unroll
  for (int i = 0; i < 3; i++) {
    float4 t = *reinterpret_cast<const float4*>(xr + i * 256 + lane * 4);
    v[i*4+0] = t.x; v[i*4+1] = t.y; v[i*4+2] = t.z; v[i*4+3] = t.w;
  }
  float s = 0.f, ss = 0.f;
#pragma unroll
  for (int i = 0; i < 12; i++) { s += v[i]; ss += v[i] * v[i]; }
#pragma unroll
  for (int off = 1; off < 64; off <<= 1) {
    s  += __shfl_xor(s, off);
    ss += __shfl_xor(ss, off);
  }
  float mu  = s * (1.f / 768.f);
  float var = ss * (1.f / 768.f) - mu * mu;
  float rs  = rsqrtf(var + 1e-5f);
  u16* orow = out + (size_t)row * EMB;
#pragma unroll
  for (int i = 0; i < 3; i++) {
    int col = i * 256 + lane * 4;
    ushort4 o;
    o.x = f2bf((v[i*4+0] - mu) * rs * g[col+0] + b[col+0]);
    o.y = f2bf((v[i*4+1] - mu) * rs * g[col+1] + b[col+1]);
    o.z = f2bf((v[i*4+2] - mu) * rs * g[col+2] + b[col+2]);
    o.w = f2bf((v[i*4+3] - mu) * rs * g[col+3] + b[col+3]);
    *reinterpret_cast<ushort4*>(orow + col) = o;
  }
}

// -------- fused prep: 6 weight transposes (fp32 (K,N) -> bf16 (N,K)) + bias --
// flat grid: [0,2304) Wq/Wk/Wv/Wo (576 each), [2304,4608) W1, [4608,6912) W2,
// [6912,6921) qkv bias concat. threads (32,8).
__global__ void prep_kernel(const float* __restrict__ Wq, const float* __restrict__ Wk,
                            const float* __restrict__ Wv, const float* __restrict__ Wo,
                            const float* __restrict__ W1, const float* __restrict__ W2,
                            u16* __restrict__ wqkv, u16* __restrict__ wot,
                            u16* __restrict__ w1t, u16* __restrict__ w2t,
                            const float* __restrict__ bq, const float* __restrict__ bk,
                            const float* __restrict__ bv, float* __restrict__ obias) {
  __shared__ float t[32][33];
  int id = blockIdx.x;
  int tx = threadIdx.x, ty = threadIdx.y;
  if (id >= 6912) {  // bias concat: 9 blocks x 256 threads
    int i = (id - 6912) * 256 + ty * 32 + tx;
    if (i < QKVD)
      obias[i] = i < EMB ? bq[i] : (i < 2*EMB ? bk[i - EMB] : bv[i - 2*EMB]);
    return;
  }
  const float* in; u16* out; int K, N, bx, by;
  if (id < 2304) {
    int seg = id / 576, rem = id % 576;
    bx = rem % 24; by = rem / 24; K = EMB; N = EMB;
    in = seg == 0 ? Wq : seg == 1 ? Wk : seg == 2 ? Wv : Wo;
    out = seg == 3 ? wot : wqkv + (size_t)seg * EMB * EMB;
  } else if (id < 4608) {
    int rem = id - 2304; bx = rem % 96; by = rem / 96;
    in = W1; out = w1t; K = EMB; N = DFF;
  } else {
    int rem = id - 4608; bx = rem % 24; by = rem / 24;
    in = W2; out = w2t; K = DFF; N = EMB;
  }
  int x0 = bx * 32, y0 = by * 32;
#pragma unroll
  for (int i = 0; i < 4; i++)
    t[ty + i*8][tx] = in[(size_t)(y0 + ty + i*8) * N + x0 + tx];
  __syncthreads();
#pragma unroll
  for (int i = 0; i < 4; i++)
    out[(size_t)(x0 + ty + i*8) * K + y0 + tx] = f2bf(t[tx][ty + i*8]);
}

// -------- GEMM: C = A(MxK,bf16) @ Bt(NxK,bf16)^T + bias, fused epilogue -----
// Proven 128x128 structure, R1-exact x-fast block order (m0=bx, n0=by).
// Ordering post-mortem (R5-R7): with >=768 co-resident blocks, A is
// L3-resident after the first residency wave; every remap tried (XCD %8,
// n-fast, stride-8 n-grouped) ADDED HBM traffic (300/330/125 MB vs 80.7).
// Lever closed - plain x-fast is the measured optimum.
// BK=64, global_load_lds 16B staging with XOR-swizzled source columns:
// LDS chunk (row r, c8) lives at position c8^(r&7) -> conflict-free b128 reads.
// MFMA operands SWAPPED (bfr, af): C^T layout => lane holds m=l16 and 4
// consecutive n = nbase+lhi*4..+3 in regs -> vectorized bias/res/store.
// mode 0: out bf16 = (acc + bias) * (n<scale_n ? scale : 1)
//         + fused V-transpose: if vtout && n>=1536, write (b,h,d,l) layout
//           directly to vtout instead of outb (kills the vtrans kernel; the
//           transposed store is 16 consecutive u16 per lhi-group = 32B segs).
// mode 1: out fp32 = acc + bias + res
// mode 2: out bf16 = gelu(acc + bias)
#define BK 64
__global__ __launch_bounds__(256) void gemm_kernel(
    const u16* __restrict__ A, const u16* __restrict__ Bt,
    const float* __restrict__ bias, const float* __restrict__ res,
    u16* __restrict__ outb, float* __restrict__ outf, u16* __restrict__ vtout,
    int M, int N, int K, int mode, float scale, int scale_n) {
  __shared__ u16 As[128 * BK];
  __shared__ u16 Bs[128 * BK];
  int tid = threadIdx.x;
  int lane = tid & 63, wave = tid >> 6;
  int wm = wave & 1, wn = wave >> 1;        // 2x2 wave grid
  int l16 = lane & 15, lhi = lane >> 4;
  int m0 = blockIdx.x * 128, n0 = blockIdx.y * 128;

  floatx4 acc[4][4];
#pragma unroll
  for (int i = 0; i < 4; i++)
#pragma unroll
    for (int j = 0; j < 4; j++) acc[i][j] = {0.f, 0.f, 0.f, 0.f};

  // ---- staging setup: one async16 covers 8 rows x 8 chunks (1024 B)
  int rr = lane >> 3;                       // row within 8-row group
  int cs = ((lane & 7) ^ rr) * 8;           // swizzled source col (shorts)
  const u16* aptr = A + (size_t)(m0 + wave * 32 + rr) * K + cs;
  const u16* bptr = Bt + (size_t)(n0 + wave * 32 + rr) * K + cs;
  u16* asl = As + (wave * 32) * BK;         // wave-uniform LDS bases
  u16* bsl = Bs + (wave * 32) * BK;

  // ---- read setup: chunk (r,c8) is at r*64 + (c8^(r&7))*8 shorts
  int l7 = l16 & 7;
  int oa0 = (wm * 64 + l16) * BK + ((lhi ^ l7) * 8);     // kk=0: c8=lhi
  int ob0 = (wn * 64 + l16) * BK + ((lhi ^ l7) * 8);
  int oa1 = oa0 ^ 32;                                     // kk=1: c8=lhi^4 -> ^(4*8)
  int ob1 = ob0 ^ 32;

  for (int k0 = 0; k0 < K; k0 += BK) {
    __syncthreads();
#pragma unroll
    for (int i = 0; i < 4; i++) {
      async16(aptr + (size_t)(i * 8) * K + k0, asl + i * 8 * BK);
      async16(bptr + (size_t)(i * 8) * K + k0, bsl + i * 8 * BK);
    }
    __syncthreads();
#pragma unroll
    for (int kk = 0; kk < 2; kk++) {
      int oA = kk ? oa1 : oa0;
      int oB = kk ? ob1 : ob0;
      short8 af[4], bfr[4];
#pragma unroll
      for (int mt = 0; mt < 4; mt++)
        af[mt] = *reinterpret_cast<const short8*>(&As[oA + mt * 16 * BK]);
#pragma unroll
      for (int nt = 0; nt < 4; nt++)
        bfr[nt] = *reinterpret_cast<const short8*>(&Bs[oB + nt * 16 * BK]);
#pragma unroll
      for (int mt = 0; mt < 4; mt++)
#pragma unroll
        for (int nt = 0; nt < 4; nt++)
          acc[mt][nt] = __builtin_amdgcn_mfma_f32_16x16x32_bf16(bfr[nt], af[mt],
                                                                acc[mt][nt], 0, 0, 0);
    }
  }

  // epilogue: lane has row m, cols nbase..nbase+3 in acc[mt][nt][0..3]
#pragma unroll
  for (int mt = 0; mt < 4; mt++) {
    int m = m0 + wm*64 + mt*16 + l16;
#pragma unroll
    for (int nt = 0; nt < 4; nt++) {
      int nbase = n0 + wn*64 + nt*16 + lhi*4;
      float4 bv = *reinterpret_cast<const float4*>(&bias[nbase]);
      float v0 = acc[mt][nt][0] + bv.x, v1 = acc[mt][nt][1] + bv.y;
      float v2 = acc[mt][nt][2] + bv.z, v3 = acc[mt][nt][3] + bv.w;
      if (mode == 1) {
        float4 r = *reinterpret_cast<const float4*>(&res[(size_t)m * N + nbase]);
        float4 o; o.x = v0 + r.x; o.y = v1 + r.y; o.z = v2 + r.z; o.w = v3 + r.w;
        *reinterpret_cast<float4*>(&outf[(size_t)m * N + nbase]) = o;
      } else if (vtout != nullptr && nbase >= 2 * EMB) {
        // fused V-transpose: (b, l) x (h*64+d) -> vt[(b*12+h)*64+d][l]
        int vcol = nbase - 2 * EMB;
        int hh = vcol >> 6, dd = vcol & 63;          // j=0..3 stays in-head
        int bb = m >> 10, l = m & 1023;
        u16* vp = vtout + ((size_t)(bb * HEADS + hh) * HD + dd) * LSEQ + l;
        vp[0]        = f2bf(v0);
        vp[LSEQ]     = f2bf(v1);
        vp[2 * LSEQ] = f2bf(v2);
        vp[3 * LSEQ] = f2bf(v3);
      } else {
        if (mode == 2) {
          v0 = gelu_fast(v0); v1 = gelu_fast(v1);
          v2 = gelu_fast(v2); v3 = gelu_fast(v3);
        } else {
          float sc = (nbase < scale_n) ? scale : 1.0f;
          v0 *= sc; v1 *= sc; v2 *= sc; v3 *= sc;
        }
        ushort4 o;
        o.x = f2bf(v0); o.y = f2bf(v1); o.z = f2bf(v2); o.w = f2bf(v3);
        *reinterpret_cast<ushort4*>(&outb[(size_t)m * N + nbase]) = o;
      }
    }
  }
}

// -------- Flash attention: LDS-staged K/V, double-buffered prefetch ---------
// K/V tile (64 seq x 64 d) staged ONCE per block via global_load_lds with the
// same XOR source-swizzle as the GEMM. Stage for tile t+1 issued at TOP of
// tile t's compute; single __syncthreads() per iteration rotates buffers.
// S^T = K.Q^T; P exits with 4 consecutive seq per lane -> b64 P writes, b128
// P^T reads; O^T = V^T.P^T.
#define PSTRIDE 76
__global__ __launch_bounds__(256) void flash_kernel(
    const u16* __restrict__ qkv, const u16* __restrict__ vt,
    u16* __restrict__ ctx) {
  __shared__ u16 Kb[2][64 * 64];
  __shared__ u16 Vb[2][64 * 64];
  __shared__ u16 Ps[4][2][16][PSTRIDE];
  int tid = threadIdx.x;
  int lane = tid & 63, w = tid >> 6;
  int l16 = lane & 15, lhi = lane >> 4;

  int i = blockIdx.x;                      // 768 = 4 qb x 192 bh, XCD-affine
  int bh = (i & 7) | ((i >> 5) << 3);      // blocks with equal (i&7, i>>5) share bh
  int qb = (i >> 3) & 3;
  int b = bh / HEADS, h = bh % HEADS;
  int q0 = qb * 256 + w * 64;              // wave's 64 q-rows

  const u16* qbase = qkv + (size_t)(b * LSEQ) * QKVD + h * HD;
  const u16* kbase = qbase + EMB;
  const u16* vbase = vt + (size_t)(bh * HD) * LSEQ;

  // ---- staging setup: wave w covers rows w*16..w*16+15 of each 64-row tile
  int rr = lane >> 3;                       // row within 8-row group
  int c8 = (lane & 7) ^ rr;                 // swizzled source chunk (8 u16)
  const u16* ksrc = kbase + (size_t)(w * 16 + rr) * QKVD + c8 * 8;
  const u16* vsrc = vbase + (size_t)(w * 16 + rr) * LSEQ + c8 * 8;

  // prologue: stage tile 0 into buffer 0
#pragma unroll
  for (int j = 0; j < 2; j++) {
    async16(ksrc + (size_t)(j * 8) * QKVD, &Kb[0][(w * 16 + j * 8) * 64]);
    async16(vsrc + (size_t)(j * 8) * LSEQ, &Vb[0][(w * 16 + j * 8) * 64]);
  }

  // Q^T B-fragments, resident: qf[st][kk] (st = q-subtile of 16)
  short8 qf[4][2];
#pragma unroll
  for (int st = 0; st < 4; st++)
#pragma unroll
    for (int kk = 0; kk < 2; kk++)
      qf[st][kk] = load16(qbase + (size_t)(q0 + st*16 + l16) * QKVD + kk*32 + lhi*8);

  floatx4 o[4][4];                          // o[st][mt]: O^T (d=mt*16+lhi*4+r, q=st*16+l16)
#pragma unroll
  for (int st = 0; st < 4; st++)
#pragma unroll
    for (int mt = 0; mt < 4; mt++) o[st][mt] = {0.f, 0.f, 0.f, 0.f};
  float l_i[4] = {0.f, 0.f, 0.f, 0.f};

  __syncthreads();                          // tile 0 landed (vmcnt drain)

  int cur = 0;
  for (int kt = 0; kt < LSEQ; kt += 64) {
    // stage tile kt+64 into buf[cur^1] (issued early, drained at loop barrier)
    if (kt + 64 < LSEQ) {
      const u16* kn = ksrc + (size_t)(kt + 64) * QKVD;
      const u16* vn = vsrc + (kt + 64);
#pragma unroll
      for (int j = 0; j < 2; j++) {
        async16(kn + (size_t)(j * 8) * QKVD, &Kb[cur ^ 1][(w * 16 + j * 8) * 64]);
        async16(vn + (size_t)(j * 8) * LSEQ, &Vb[cur ^ 1][(w * 16 + j * 8) * 64]);
      }
    }

    // K A-fragments (m=seq, k=d) and V^T A-fragments (m=d, k=seq) from LDS
    short8 kf[4][2], vf[4][2];
#pragma unroll
    for (int mt = 0; mt < 4; mt++) {
      int krow = mt * 16 + l16;             // K: seq-in-tile; V: d
#pragma unroll
      for (int kk = 0; kk < 2; kk++) {
        int slot = ((kk * 4 + lhi) ^ (krow & 7)) * 8;
        kf[mt][kk] = load16(&Kb[cur][krow * 64 + slot]);
        vf[mt][kk] = load16(&Vb[cur][krow * 64 + slot]);
      }
    }

#pragma unroll
    for (int st = 0; st < 4; st++) {
      u16* pbuf = &Ps[w][st & 1][0][0];
      floatx4 s[4];
#pragma unroll
      for (int mt = 0; mt < 4; mt++) s[mt] = {0.f, 0.f, 0.f, 0.f};
#pragma unroll
      for (int mt = 0; mt < 4; mt++)
#pragma unroll
        for (int kk = 0; kk < 2; kk++)
          s[mt] = __builtin_amdgcn_mfma_f32_16x16x32_bf16(kf[mt][kk], qf[st][kk],
                                                          s[mt], 0, 0, 0);
      // p = exp2(s); lane-local row partial (q = l16 fixed for this lane)
      float ls = 0.f;
#pragma unroll
      for (int mt = 0; mt < 4; mt++) {
        ushort4 pw;
        float p0 = fast_exp2(s[mt][0]), p1 = fast_exp2(s[mt][1]);
        float p2 = fast_exp2(s[mt][2]), p3 = fast_exp2(s[mt][3]);
        ls += (p0 + p1) + (p2 + p3);
        pw.x = f2bf_trunc(p0); pw.y = f2bf_trunc(p1);
        pw.z = f2bf_trunc(p2); pw.w = f2bf_trunc(p3);
        *reinterpret_cast<ushort4*>(&pbuf[l16 * PSTRIDE + mt*16 + lhi*4]) = pw;
      }
      l_i[st] += ls;
      // P^T B-fragments (k=seq, n=q) — contiguous b128
      short8 pf0 = load16(&pbuf[l16 * PSTRIDE + 0*32 + lhi*8]);
      short8 pf1 = load16(&pbuf[l16 * PSTRIDE + 1*32 + lhi*8]);
#pragma unroll
      for (int mt = 0; mt < 4; mt++) {
        o[st][mt] = __builtin_amdgcn_mfma_f32_16x16x32_bf16(vf[mt][0], pf0,
                                                            o[st][mt], 0, 0, 0);
        o[st][mt] = __builtin_amdgcn_mfma_f32_16x16x32_bf16(vf[mt][1], pf1,
                                                            o[st][mt], 0, 0, 0);
      }
    }

    __syncthreads();                        // buffer rotate + stage drain
    cur ^= 1;
  }

  // reduce row sums across the 4 lhi groups (lanes 16/32/48 apart)
#pragma unroll
  for (int st = 0; st < 4; st++) {
    l_i[st] += __shfl_xor(l_i[st], 16);
    l_i[st] += __shfl_xor(l_i[st], 32);
  }

#pragma unroll
  for (int st = 0; st < 4; st++) {
    float inv = fast_rcp(l_i[st]);
    size_t rowbase = (size_t)(b * LSEQ + q0 + st*16 + l16) * EMB + h * HD;
#pragma unroll
    for (int mt = 0; mt < 4; mt++) {
      ushort4 ow;
      ow.x = f2bf(o[st][mt][0] * inv); ow.y = f2bf(o[st][mt][1] * inv);
      ow.z = f2bf(o[st][mt][2] * inv); ow.w = f2bf(o[st][mt][3] * inv);
      *reinterpret_cast<ushort4*>(&ctx[rowbase + mt*16 + lhi*4]) = ow;
    }
  }
}

extern "C" void kernel_launch(void* const* d_in, const int* in_sizes, int n_in,
                              void* d_out, int out_size, void* d_ws, size_t ws_size,
                              hipStream_t stream) {
  const float* x    = (const float*)d_in[0];
  const float* ln1g = (const float*)d_in[1];
  const float* ln1b = (const float*)d_in[2];
  const float* Wq   = (const float*)d_in[3];
  const float* bq   = (const float*)d_in[4];
  const float* Wk   = (const float*)d_in[5];
  const float* bk   = (const float*)d_in[6];
  const float* Wv   = (const float*)d_in[7];
  const float* bv   = (const float*)d_in[8];
  const float* Wo   = (const float*)d_in[9];
  const float* bo   = (const float*)d_in[10];
  const float* ln2g = (const float*)d_in[11];
  const float* ln2b = (const float*)d_in[12];
  const float* W1   = (const float*)d_in[13];
  const float* b1   = (const float*)d_in[14];
  const float* W2   = (const float*)d_in[15];
  const float* b2   = (const float*)d_in[16];

  char* ws = (char*)d_ws;
  // activations
  u16* qkv_bf = (u16*)(ws);                               // [BL][2304]  75.5 MB
  u16* vt_bf  = (u16*)(ws + (size_t)75497472);            // [192*64][1024] 25.2 MB
  u16* h_bf   = (u16*)(ws + (size_t)100663296);           // [BL][768]   25.2 MB
  float* x2   = (float*)(ws + (size_t)125829120);         // [BL][768]f32 50.3 MB
  u16* m_bf   = (u16*)(ws);                               // [BL][3072] aliases qkv+vt
  // weights (bf16, transposed)
  char* wp = ws + (size_t)176160768;
  u16* wqkv = (u16*)(wp);                                 // [2304][768]
  u16* wot  = (u16*)(wp + (size_t)3538944);
  u16* w1t  = (u16*)(wp + (size_t)3538944 + 1179648);     // [3072][768]
  u16* w2t  = (u16*)(wp + (size_t)3538944 + 1179648 + 4718592); // [768][3072]
  float* qkvbias = (float*)(wp + (size_t)3538944 + 1179648 + 2*4718592);

  dim3 b256(256), tb(32, 8);

  prep_kernel<<<dim3(6921), tb, 0, stream>>>(Wq, Wk, Wv, Wo, W1, W2,
      wqkv, wot, w1t, w2t, bq, bk, bv, qkvbias);

  ln_kernel<<<dim3(BL/4), b256, 0, stream>>>(x, ln1g, ln1b, h_bf);

  // fused QKV: N=2304; q columns get QSCALE folded in (softmax exp2 domain);
  // V columns (n>=1536) stream directly to vt_bf in (b,h,d,l) layout.
  gemm_kernel<<<dim3(128, 18), b256, 0, stream>>>(h_bf, wqkv, qkvbias, nullptr,
      qkv_bf, nullptr, vt_bf, BL, QKVD, EMB, 0, QSCALE, EMB);

  flash_kernel<<<dim3(768), b256, 0, stream>>>(qkv_bf, vt_bf, h_bf);

  gemm_kernel<<<dim3(128, 6), b256, 0, stream>>>(h_bf, wot, bo, x, nullptr, x2,
      nullptr, BL, EMB, EMB, 1, 1.0f, 0);

  ln_kernel<<<dim3(BL/4), b256, 0, stream>>>(x2, ln2g, ln2b, h_bf);

  gemm_kernel<<<dim3(128, 24), b256, 0, stream>>>(h_bf, w1t, b1, nullptr, m_bf,
      nullptr, nullptr, BL, DFF, EMB, 2, 1.0f, 0);

  gemm_kernel<<<dim3(128, 6), b256, 0, stream>>>(m_bf, w2t, b2, x2, nullptr,
      (float*)d_out, nullptr, BL, EMB, DFF, 1, 1.0f, 0);
}

// Round 9
// 603.715 us; speedup vs baseline: 1.0553x; 1.0553x over previous
//
#include <hip/hip_runtime.h>
#include <hip/hip_bf16.h>
#include <math.h>

#define EMB 768
#define DFF 3072
#define HEADS 12
#define HD 64
#define LSEQ 1024
#define BATCH 16
#define BL (BATCH * LSEQ)   // 16384 rows
#define QKVD 2304           // fused q|k|v column dim
#define QSCALE 0.1803368801111204f  // (1/sqrt(64)) * log2(e)

typedef __attribute__((ext_vector_type(8))) short short8;
typedef __attribute__((ext_vector_type(4))) float floatx4;
typedef unsigned short u16;

__device__ __forceinline__ u16 f2bf(float f) {
  union { float f; unsigned u; } c; c.f = f;
  unsigned u = c.u;
  u += 0x7fffu + ((u >> 16) & 1u);   // round-to-nearest-even
  return (u16)(u >> 16);
}
__device__ __forceinline__ u16 f2bf_trunc(float f) {  // cheap: 1 op, ~0.4% err
  union { float f; unsigned u; } c; c.f = f;
  return (u16)(c.u >> 16);
}
__device__ __forceinline__ float fast_exp2(float x) {
#if __has_builtin(__builtin_amdgcn_exp2f)
  return __builtin_amdgcn_exp2f(x);
#else
  return exp2f(x);
#endif
}
__device__ __forceinline__ float fast_rcp(float x) {
#if __has_builtin(__builtin_amdgcn_rcpf)
  return __builtin_amdgcn_rcpf(x);
#else
  return 1.0f / x;
#endif
}
// gelu exact-erf replacement: tanh form via exp2; |err| <~1e-3, clamped safe
__device__ __forceinline__ float gelu_fast(float x) {
  float x2 = x * x;
  float u = x * fmaf(0.10294540f, x2, 2.30211423f);  // = 2*log2e*0.7978846*(x+0.044715x^3)
  u = fminf(fmaxf(u, -30.f), 30.f);
  float t = fast_exp2(u);
  return x * t * fast_rcp(t + 1.0f);                  // x * sigmoid(2v)
}
// async global->LDS, 16B per lane; lds dest = wave-uniform base + lane*16
__device__ __forceinline__ void async16(const u16* g, u16* l) {
  __builtin_amdgcn_global_load_lds(
      (const __attribute__((address_space(1))) unsigned int*)g,
      (__attribute__((address_space(3))) unsigned int*)l, 16, 0, 0);
}
__device__ __forceinline__ short8 load16(const u16* p) {
  return *reinterpret_cast<const short8*>(p);
}

// ---------------- LayerNorm: fp32 in -> bf16 out (one wave per row) ----------
__global__ __launch_bounds__(256) void ln_kernel(const float* __restrict__ x,
                                                 const float* __restrict__ g,
                                                 const float* __restrict__ b,
                                                 u16* __restrict__ out) {
  int row = blockIdx.x * 4 + (threadIdx.x >> 6);
  int lane = threadIdx.x & 63;
  const float* xr = x + (size_t)row * EMB;
  float v[12];
#pragma unroll
  for (int i = 0; i < 3; i++) {
    float4 t = *reinterpret_cast<const float4*>(xr + i * 256 + lane * 4);
    v[i*4+0] = t.x; v[i*4+1] = t.y; v[i*4+2] = t.z; v[i*4+3] = t.w;
  }
  float s = 0.f, ss = 0.f;
#pragma unroll
  for (int i = 0; i < 12; i++) { s += v[i]; ss += v[i] * v[i]; }
#pragma unroll
  for (int off = 1; off < 64; off <<= 1) {
    s  += __shfl_xor(s, off);
    ss += __shfl_xor(ss, off);
  }
  float mu  = s * (1.f / 768.f);
  float var = ss * (1.f / 768.f) - mu * mu;
  float rs  = rsqrtf(var + 1e-5f);
  u16* orow = out + (size_t)row * EMB;
#pragma unroll
  for (int i = 0; i < 3; i++) {
    int col = i * 256 + lane * 4;
    ushort4 o;
    o.x = f2bf((v[i*4+0] - mu) * rs * g[col+0] + b[col+0]);
    o.y = f2bf((v[i*4+1] - mu) * rs * g[col+1] + b[col+1]);
    o.z = f2bf((v[i*4+2] - mu) * rs * g[col+2] + b[col+2]);
    o.w = f2bf((v[i*4+3] - mu) * rs * g[col+3] + b[col+3]);
    *reinterpret_cast<ushort4*>(orow + col) = o;
  }
}

// -------- fused prep: 6 weight transposes (fp32 (K,N) -> bf16 (N,K)) + bias --
__global__ void prep_kernel(const float* __restrict__ Wq, const float* __restrict__ Wk,
                            const float* __restrict__ Wv, const float* __restrict__ Wo,
                            const float* __restrict__ W1, const float* __restrict__ W2,
                            u16* __restrict__ wqkv, u16* __restrict__ wot,
                            u16* __restrict__ w1t, u16* __restrict__ w2t,
                            const float* __restrict__ bq, const float* __restrict__ bk,
                            const float* __restrict__ bv, float* __restrict__ obias) {
  __shared__ float t[32][33];
  int id = blockIdx.x;
  int tx = threadIdx.x, ty = threadIdx.y;
  if (id >= 6912) {  // bias concat: 9 blocks x 256 threads
    int i = (id - 6912) * 256 + ty * 32 + tx;
    if (i < QKVD)
      obias[i] = i < EMB ? bq[i] : (i < 2*EMB ? bk[i - EMB] : bv[i - 2*EMB]);
    return;
  }
  const float* in; u16* out; int K, N, bx, by;
  if (id < 2304) {
    int seg = id / 576, rem = id % 576;
    bx = rem % 24; by = rem / 24; K = EMB; N = EMB;
    in = seg == 0 ? Wq : seg == 1 ? Wk : seg == 2 ? Wv : Wo;
    out = seg == 3 ? wot : wqkv + (size_t)seg * EMB * EMB;
  } else if (id < 4608) {
    int rem = id - 2304; bx = rem % 96; by = rem / 96;
    in = W1; out = w1t; K = EMB; N = DFF;
  } else {
    int rem = id - 4608; bx = rem % 24; by = rem / 24;
    in = W2; out = w2t; K = DFF; N = EMB;
  }
  int x0 = bx * 32, y0 = by * 32;
#pragma unroll
  for (int i = 0; i < 4; i++)
    t[ty + i*8][tx] = in[(size_t)(y0 + ty + i*8) * N + x0 + tx];
  __syncthreads();
#pragma unroll
  for (int i = 0; i < 4; i++)
    out[(size_t)(x0 + ty + i*8) * K + y0 + tx] = f2bf(t[tx][ty + i*8]);
}

// -------- V transpose (bf16): qkv (b,l,1536+h*64+d) -> (b,h,d,l) ------------
__global__ void vtrans_kernel(const u16* __restrict__ qkv, u16* __restrict__ vt) {
  __shared__ u16 t[32][33];
  int l0 = blockIdx.x * 32;
  int d0 = blockIdx.y * 32;
  int bh = blockIdx.z;
  int b = bh / HEADS, h = bh % HEADS;
  int tx = threadIdx.x, ty = threadIdx.y;  // 32 x 8
#pragma unroll
  for (int i = 0; i < 4; i++)
    t[ty + i*8][tx] = qkv[(size_t)(b * LSEQ + l0 + ty + i*8) * QKVD + 2*EMB + h * HD + d0 + tx];
  __syncthreads();
#pragma unroll
  for (int i = 0; i < 4; i++)
    vt[(size_t)(bh * HD + d0 + ty + i*8) * LSEQ + l0 + tx] = t[tx][ty + i*8];
}

// -------- GEMM 128x128 (proven R1, x-fast) — used for Wo --------------------
#define BK 64
__global__ __launch_bounds__(256) void gemm_kernel(
    const u16* __restrict__ A, const u16* __restrict__ Bt,
    const float* __restrict__ bias, const float* __restrict__ res,
    u16* __restrict__ outb, float* __restrict__ outf,
    int M, int N, int K, int mode, float scale, int scale_n) {
  __shared__ u16 As[128 * BK];
  __shared__ u16 Bs[128 * BK];
  int tid = threadIdx.x;
  int lane = tid & 63, wave = tid >> 6;
  int wm = wave & 1, wn = wave >> 1;        // 2x2 wave grid
  int l16 = lane & 15, lhi = lane >> 4;
  int m0 = blockIdx.x * 128, n0 = blockIdx.y * 128;

  floatx4 acc[4][4];
#pragma unroll
  for (int i = 0; i < 4; i++)
#pragma unroll
    for (int j = 0; j < 4; j++) acc[i][j] = {0.f, 0.f, 0.f, 0.f};

  int rr = lane >> 3;
  int cs = ((lane & 7) ^ rr) * 8;
  const u16* aptr = A + (size_t)(m0 + wave * 32 + rr) * K + cs;
  const u16* bptr = Bt + (size_t)(n0 + wave * 32 + rr) * K + cs;
  u16* asl = As + (wave * 32) * BK;
  u16* bsl = Bs + (wave * 32) * BK;

  int l7 = l16 & 7;
  int oa0 = (wm * 64 + l16) * BK + ((lhi ^ l7) * 8);
  int ob0 = (wn * 64 + l16) * BK + ((lhi ^ l7) * 8);
  int oa1 = oa0 ^ 32;
  int ob1 = ob0 ^ 32;

  for (int k0 = 0; k0 < K; k0 += BK) {
    __syncthreads();
#pragma unroll
    for (int i = 0; i < 4; i++) {
      async16(aptr + (size_t)(i * 8) * K + k0, asl + i * 8 * BK);
      async16(bptr + (size_t)(i * 8) * K + k0, bsl + i * 8 * BK);
    }
    __syncthreads();
#pragma unroll
    for (int kk = 0; kk < 2; kk++) {
      int oA = kk ? oa1 : oa0;
      int oB = kk ? ob1 : ob0;
      short8 af[4], bfr[4];
#pragma unroll
      for (int mt = 0; mt < 4; mt++)
        af[mt] = *reinterpret_cast<const short8*>(&As[oA + mt * 16 * BK]);
#pragma unroll
      for (int nt = 0; nt < 4; nt++)
        bfr[nt] = *reinterpret_cast<const short8*>(&Bs[oB + nt * 16 * BK]);
#pragma unroll
      for (int mt = 0; mt < 4; mt++)
#pragma unroll
        for (int nt = 0; nt < 4; nt++)
          acc[mt][nt] = __builtin_amdgcn_mfma_f32_16x16x32_bf16(bfr[nt], af[mt],
                                                                acc[mt][nt], 0, 0, 0);
    }
  }

#pragma unroll
  for (int mt = 0; mt < 4; mt++) {
    int m = m0 + wm*64 + mt*16 + l16;
#pragma unroll
    for (int nt = 0; nt < 4; nt++) {
      int nbase = n0 + wn*64 + nt*16 + lhi*4;
      float4 bv = *reinterpret_cast<const float4*>(&bias[nbase]);
      float v0 = acc[mt][nt][0] + bv.x, v1 = acc[mt][nt][1] + bv.y;
      float v2 = acc[mt][nt][2] + bv.z, v3 = acc[mt][nt][3] + bv.w;
      if (mode == 1) {
        float4 r = *reinterpret_cast<const float4*>(&res[(size_t)m * N + nbase]);
        float4 o; o.x = v0 + r.x; o.y = v1 + r.y; o.z = v2 + r.z; o.w = v3 + r.w;
        *reinterpret_cast<float4*>(&outf[(size_t)m * N + nbase]) = o;
      } else {
        if (mode == 2) {
          v0 = gelu_fast(v0); v1 = gelu_fast(v1);
          v2 = gelu_fast(v2); v3 = gelu_fast(v3);
        } else {
          float sc = (nbase < scale_n) ? scale : 1.0f;
          v0 *= sc; v1 *= sc; v2 *= sc; v3 *= sc;
        }
        ushort4 o;
        o.x = f2bf(v0); o.y = f2bf(v1); o.z = f2bf(v2); o.w = f2bf(v3);
        *reinterpret_cast<ushort4*>(&outb[(size_t)m * N + nbase]) = o;
      }
    }
  }
}

// -------- GEMM 256x256 / 8-wave / 4-phase, single-read fragments ------------
// Corrected m201-style port (R2/R4 failed by reading each fragment 2x -> LDS
// pipe 4600cyc/tile vs MFMA 2500; this version reads each ONCE: 24 b128 per
// 64 MFMA per wave per K-tile -> LDS 2300 ~ MFMA 2500, balanced).
// Waves 2(M)x4(N); per-wave output 128x64; acc[8][4]. dbuf 128KiB LDS,
// 1 block/CU. Per K-tile t (buf c=t&1):
//   P1 (mh0,kk0): read 4 A + 4 B frags | stage ALL 8 loads of tile t+1 into
//                 buf c^1 | bar | 16 MFMA | bar
//   P2 (mh1,kk0): read 4 A (REUSE B regs)| bar | 16 MFMA | bar
//   P3 (mh0,kk1): read 4 A + 4 B        | bar | 16 MFMA | bar
//   P4 (mh1,kk1): read 4 A (reuse B)    | bar | 16 MFMA | vmcnt(0)* | bar
// (*) drains only tile t+1's loads, issued 3 phases (~1900cyc) earlier ->
// near-free; "never drain young loads" holds. Opposite-buffer staging makes
// overwrite hazard impossible (tile t-1, same parity, finished reads before
// the end-P4(t-1) barrier). Raw s_barrier (no vmcnt0/lgkmcnt0 drain) + a
// zero-cost compiler fence after each barrier so next-phase LDS reads can't
// be hoisted above it. Same XOR swizzle + fragment math as proven kernel.
__global__ __launch_bounds__(512, 2) void gemm256_kernel(
    const u16* __restrict__ A, const u16* __restrict__ Bt,
    const float* __restrict__ bias, const float* __restrict__ res,
    u16* __restrict__ outb, float* __restrict__ outf,
    int M, int N, int K, int mode, float scale, int scale_n) {
  __shared__ u16 As[2][256 * 64];
  __shared__ u16 Bs[2][256 * 64];
  int tid = threadIdx.x;
  int lane = tid & 63, wave = tid >> 6;
  int wm = wave >> 2, wn = wave & 3;        // 2(M) x 4(N)
  int l16 = lane & 15, lhi = lane >> 4, l7 = l16 & 7;
  int m0 = blockIdx.x * 256, n0 = blockIdx.y * 256;

  floatx4 acc[8][4];
#pragma unroll
  for (int i = 0; i < 8; i++)
#pragma unroll
    for (int j = 0; j < 4; j++) acc[i][j] = {0.f, 0.f, 0.f, 0.f};

  // staging: one async16 = wave's 8 rows x 8 chunks (1KB LDS, contiguous).
  // 8 calls (4 A row-groups + 4 B row-groups of 64 rows) cover one K-tile.
  int rr = lane >> 3;
  int cs = ((lane & 7) ^ rr) * 8;           // pre-swizzled source chunk
  const u16* aptr = A + (size_t)(m0 + wave * 8 + rr) * K + cs;
  const u16* bptr = Bt + (size_t)(n0 + wave * 8 + rr) * K + cs;

  auto stage_all = [&](int nb, int k0) {
#pragma unroll
    for (int g = 0; g < 4; g++)
      async16(aptr + (size_t)(g * 64) * K + k0, &As[nb][(g * 64 + wave * 8) * 64]);
#pragma unroll
    for (int g = 0; g < 4; g++)
      async16(bptr + (size_t)(g * 64) * K + k0, &Bs[nb][(g * 64 + wave * 8) * 64]);
  };

  // prologue: tile 0 staged + drained
  stage_all(0, 0);
  asm volatile("s_waitcnt vmcnt(0)" ::: "memory");
  __builtin_amdgcn_s_barrier();
  asm volatile("" ::: "memory");

  // read bases: frag row -> row*64 + ((c8 ^ (row&7))*8); kk toggles slot ^32
  int oa = (wm * 128 + l16) * 64 + ((lhi ^ l7) * 8);
  int ob = (wn * 64 + l16) * 64 + ((lhi ^ l7) * 8);
  short8 bfr[4];

  int NT = K >> 6;
  for (int t = 0; t < NT; t++) {
    int cur = t & 1;
    const u16* pa = As[cur];
    const u16* pb = Bs[cur];
    bool pre = (t + 1 < NT);
#pragma unroll
    for (int ph = 0; ph < 4; ph++) {
      int mh = ph & 1, kk = ph >> 1;
      short8 af[4];
#pragma unroll
      for (int mt4 = 0; mt4 < 4; mt4++) {
        int o = oa + (mh * 64 + mt4 * 16) * 64;
        af[mt4] = load16(&pa[kk ? (o ^ 32) : o]);
      }
      if (mh == 0) {
#pragma unroll
        for (int nt = 0; nt < 4; nt++) {
          int o = ob + nt * 16 * 64;
          bfr[nt] = load16(&pb[kk ? (o ^ 32) : o]);
        }
      }
      if (ph == 0 && pre) stage_all(cur ^ 1, (t + 1) << 6);
      __builtin_amdgcn_s_barrier();
      asm volatile("" ::: "memory");
      __builtin_amdgcn_s_setprio(1);
#pragma unroll
      for (int mt4 = 0; mt4 < 4; mt4++)
#pragma unroll
        for (int nt = 0; nt < 4; nt++)
          acc[mh * 4 + mt4][nt] = __builtin_amdgcn_mfma_f32_16x16x32_bf16(
              bfr[nt], af[mt4], acc[mh * 4 + mt4][nt], 0, 0, 0);
      __builtin_amdgcn_s_setprio(0);
      if (ph == 3 && pre) asm volatile("s_waitcnt vmcnt(0)" ::: "memory");
      __builtin_amdgcn_s_barrier();
      asm volatile("" ::: "memory");
    }
  }

  // epilogue: lane has row m, cols nbase..nbase+3 in acc[mi][ni][0..3]
#pragma unroll
  for (int mi = 0; mi < 8; mi++) {
    int m = m0 + wm * 128 + mi * 16 + l16;
#pragma unroll
    for (int ni = 0; ni < 4; ni++) {
      int nbase = n0 + wn * 64 + ni * 16 + lhi * 4;
      float4 bv = *reinterpret_cast<const float4*>(&bias[nbase]);
      float v0 = acc[mi][ni][0] + bv.x, v1 = acc[mi][ni][1] + bv.y;
      float v2 = acc[mi][ni][2] + bv.z, v3 = acc[mi][ni][3] + bv.w;
      if (mode == 1) {
        float4 r = *reinterpret_cast<const float4*>(&res[(size_t)m * N + nbase]);
        float4 o; o.x = v0 + r.x; o.y = v1 + r.y; o.z = v2 + r.z; o.w = v3 + r.w;
        *reinterpret_cast<float4*>(&outf[(size_t)m * N + nbase]) = o;
      } else {
        if (mode == 2) {
          v0 = gelu_fast(v0); v1 = gelu_fast(v1);
          v2 = gelu_fast(v2); v3 = gelu_fast(v3);
        } else {
          float sc = (nbase < scale_n) ? scale : 1.0f;
          v0 *= sc; v1 *= sc; v2 *= sc; v3 *= sc;
        }
        ushort4 o;
        o.x = f2bf(v0); o.y = f2bf(v1); o.z = f2bf(v2); o.w = f2bf(v3);
        *reinterpret_cast<ushort4*>(&outb[(size_t)m * N + nbase]) = o;
      }
    }
  }
}

// -------- Flash attention: LDS-staged K/V, double-buffered prefetch ---------
#define PSTRIDE 76
__global__ __launch_bounds__(256) void flash_kernel(
    const u16* __restrict__ qkv, const u16* __restrict__ vt,
    u16* __restrict__ ctx) {
  __shared__ u16 Kb[2][64 * 64];
  __shared__ u16 Vb[2][64 * 64];
  __shared__ u16 Ps[4][2][16][PSTRIDE];
  int tid = threadIdx.x;
  int lane = tid & 63, w = tid >> 6;
  int l16 = lane & 15, lhi = lane >> 4;

  int i = blockIdx.x;                      // 768 = 4 qb x 192 bh, XCD-affine
  int bh = (i & 7) | ((i >> 5) << 3);
  int qb = (i >> 3) & 3;
  int b = bh / HEADS, h = bh % HEADS;
  int q0 = qb * 256 + w * 64;

  const u16* qbase = qkv + (size_t)(b * LSEQ) * QKVD + h * HD;
  const u16* kbase = qbase + EMB;
  const u16* vbase = vt + (size_t)(bh * HD) * LSEQ;

  int rr = lane >> 3;
  int c8 = (lane & 7) ^ rr;
  const u16* ksrc = kbase + (size_t)(w * 16 + rr) * QKVD + c8 * 8;
  const u16* vsrc = vbase + (size_t)(w * 16 + rr) * LSEQ + c8 * 8;

#pragma unroll
  for (int j = 0; j < 2; j++) {
    async16(ksrc + (size_t)(j * 8) * QKVD, &Kb[0][(w * 16 + j * 8) * 64]);
    async16(vsrc + (size_t)(j * 8) * LSEQ, &Vb[0][(w * 16 + j * 8) * 64]);
  }

  short8 qf[4][2];
#pragma unroll
  for (int st = 0; st < 4; st++)
#pragma unroll
    for (int kk = 0; kk < 2; kk++)
      qf[st][kk] = load16(qbase + (size_t)(q0 + st*16 + l16) * QKVD + kk*32 + lhi*8);

  floatx4 o[4][4];
#pragma unroll
  for (int st = 0; st < 4; st++)
#pragma unroll
    for (int mt = 0; mt < 4; mt++) o[st][mt] = {0.f, 0.f, 0.f, 0.f};
  float l_i[4] = {0.f, 0.f, 0.f, 0.f};

  __syncthreads();

  int cur = 0;
  for (int kt = 0; kt < LSEQ; kt += 64) {
    if (kt + 64 < LSEQ) {
      const u16* kn = ksrc + (size_t)(kt + 64) * QKVD;
      const u16* vn = vsrc + (kt + 64);
#pragma unroll
      for (int j = 0; j < 2; j++) {
        async16(kn + (size_t)(j * 8) * QKVD, &Kb[cur ^ 1][(w * 16 + j * 8) * 64]);
        async16(vn + (size_t)(j * 8) * LSEQ, &Vb[cur ^ 1][(w * 16 + j * 8) * 64]);
      }
    }

    short8 kf[4][2], vf[4][2];
#pragma unroll
    for (int mt = 0; mt < 4; mt++) {
      int krow = mt * 16 + l16;
#pragma unroll
      for (int kk = 0; kk < 2; kk++) {
        int slot = ((kk * 4 + lhi) ^ (krow & 7)) * 8;
        kf[mt][kk] = load16(&Kb[cur][krow * 64 + slot]);
        vf[mt][kk] = load16(&Vb[cur][krow * 64 + slot]);
      }
    }

#pragma unroll
    for (int st = 0; st < 4; st++) {
      u16* pbuf = &Ps[w][st & 1][0][0];
      floatx4 s[4];
#pragma unroll
      for (int mt = 0; mt < 4; mt++) s[mt] = {0.f, 0.f, 0.f, 0.f};
#pragma unroll
      for (int mt = 0; mt < 4; mt++)
#pragma unroll
        for (int kk = 0; kk < 2; kk++)
          s[mt] = __builtin_amdgcn_mfma_f32_16x16x32_bf16(kf[mt][kk], qf[st][kk],
                                                          s[mt], 0, 0, 0);
      float ls = 0.f;
#pragma unroll
      for (int mt = 0; mt < 4; mt++) {
        ushort4 pw;
        float p0 = fast_exp2(s[mt][0]), p1 = fast_exp2(s[mt][1]);
        float p2 = fast_exp2(s[mt][2]), p3 = fast_exp2(s[mt][3]);
        ls += (p0 + p1) + (p2 + p3);
        pw.x = f2bf_trunc(p0); pw.y = f2bf_trunc(p1);
        pw.z = f2bf_trunc(p2); pw.w = f2bf_trunc(p3);
        *reinterpret_cast<ushort4*>(&pbuf[l16 * PSTRIDE + mt*16 + lhi*4]) = pw;
      }
      l_i[st] += ls;
      short8 pf0 = load16(&pbuf[l16 * PSTRIDE + 0*32 + lhi*8]);
      short8 pf1 = load16(&pbuf[l16 * PSTRIDE + 1*32 + lhi*8]);
#pragma unroll
      for (int mt = 0; mt < 4; mt++) {
        o[st][mt] = __builtin_amdgcn_mfma_f32_16x16x32_bf16(vf[mt][0], pf0,
                                                            o[st][mt], 0, 0, 0);
        o[st][mt] = __builtin_amdgcn_mfma_f32_16x16x32_bf16(vf[mt][1], pf1,
                                                            o[st][mt], 0, 0, 0);
      }
    }

    __syncthreads();
    cur ^= 1;
  }

#pragma unroll
  for (int st = 0; st < 4; st++) {
    l_i[st] += __shfl_xor(l_i[st], 16);
    l_i[st] += __shfl_xor(l_i[st], 32);
  }

#pragma unroll
  for (int st = 0; st < 4; st++) {
    float inv = fast_rcp(l_i[st]);
    size_t rowbase = (size_t)(b * LSEQ + q0 + st*16 + l16) * EMB + h * HD;
#pragma unroll
    for (int mt = 0; mt < 4; mt++) {
      ushort4 ow;
      ow.x = f2bf(o[st][mt][0] * inv); ow.y = f2bf(o[st][mt][1] * inv);
      ow.z = f2bf(o[st][mt][2] * inv); ow.w = f2bf(o[st][mt][3] * inv);
      *reinterpret_cast<ushort4*>(&ctx[rowbase + mt*16 + lhi*4]) = ow;
    }
  }
}

extern "C" void kernel_launch(void* const* d_in, const int* in_sizes, int n_in,
                              void* d_out, int out_size, void* d_ws, size_t ws_size,
                              hipStream_t stream) {
  const float* x    = (const float*)d_in[0];
  const float* ln1g = (const float*)d_in[1];
  const float* ln1b = (const float*)d_in[2];
  const float* Wq   = (const float*)d_in[3];
  const float* bq   = (const float*)d_in[4];
  const float* Wk   = (const float*)d_in[5];
  const float* bk   = (const float*)d_in[6];
  const float* Wv   = (const float*)d_in[7];
  const float* bv   = (const float*)d_in[8];
  const float* Wo   = (const float*)d_in[9];
  const float* bo   = (const float*)d_in[10];
  const float* ln2g = (const float*)d_in[11];
  const float* ln2b = (const float*)d_in[12];
  const float* W1   = (const float*)d_in[13];
  const float* b1   = (const float*)d_in[14];
  const float* W2   = (const float*)d_in[15];
  const float* b2   = (const float*)d_in[16];

  char* ws = (char*)d_ws;
  // activations
  u16* qkv_bf = (u16*)(ws);                               // [BL][2304]  75.5 MB
  u16* vt_bf  = (u16*)(ws + (size_t)75497472);            // [192*64][1024] 25.2 MB
  u16* h_bf   = (u16*)(ws + (size_t)100663296);           // [BL][768]   25.2 MB
  float* x2   = (float*)(ws + (size_t)125829120);         // [BL][768]f32 50.3 MB
  u16* m_bf   = (u16*)(ws);                               // [BL][3072] aliases qkv+vt
  // weights (bf16, transposed)
  char* wp = ws + (size_t)176160768;
  u16* wqkv = (u16*)(wp);                                 // [2304][768]
  u16* wot  = (u16*)(wp + (size_t)3538944);
  u16* w1t  = (u16*)(wp + (size_t)3538944 + 1179648);     // [3072][768]
  u16* w2t  = (u16*)(wp + (size_t)3538944 + 1179648 + 4718592); // [768][3072]
  float* qkvbias = (float*)(wp + (size_t)3538944 + 1179648 + 2*4718592);

  dim3 b256(256), b512(512), tb(32, 8);

  prep_kernel<<<dim3(6921), tb, 0, stream>>>(Wq, Wk, Wv, Wo, W1, W2,
      wqkv, wot, w1t, w2t, bq, bk, bv, qkvbias);

  ln_kernel<<<dim3(BL/4), b256, 0, stream>>>(x, ln1g, ln1b, h_bf);

  // fused QKV: N=2304; q columns get QSCALE folded in (softmax exp2 domain)
  gemm256_kernel<<<dim3(64, 9), b512, 0, stream>>>(h_bf, wqkv, qkvbias, nullptr,
      qkv_bf, nullptr, BL, QKVD, EMB, 0, QSCALE, EMB);

  vtrans_kernel<<<dim3(32, 2, BATCH*HEADS), tb, 0, stream>>>(qkv_bf, vt_bf);

  flash_kernel<<<dim3(768), b256, 0, stream>>>(qkv_bf, vt_bf, h_bf);

  gemm_kernel<<<dim3(128, 6), b256, 0, stream>>>(h_bf, wot, bo, x, nullptr, x2,
      BL, EMB, EMB, 1, 1.0f, 0);

  ln_kernel<<<dim3(BL/4), b256, 0, stream>>>(x2, ln2g, ln2b, h_bf);

  gemm256_kernel<<<dim3(64, 12), b512, 0, stream>>>(h_bf, w1t, b1, nullptr, m_bf,
      nullptr, BL, DFF, EMB, 2, 1.0f, 0);

  gemm256_kernel<<<dim3(64, 3), b512, 0, stream>>>(m_bf, w2t, b2, x2, nullptr,
      (float*)d_out, BL, EMB, DFF, 1, 1.0f, 0);
}

// Round 10
// 559.698 us; speedup vs baseline: 1.1383x; 1.0786x over previous
//
#include <hip/hip_runtime.h>
#include <hip/hip_bf16.h>
#include <math.h>

#define EMB 768
#define DFF 3072
#define HEADS 12
#define HD 64
#define LSEQ 1024
#define BATCH 16
#define BL (BATCH * LSEQ)   // 16384 rows
#define QKVD 2304           // fused q|k|v column dim
#define QSCALE 0.1803368801111204f  // (1/sqrt(64)) * log2(e)

typedef __attribute__((ext_vector_type(8))) short short8;
typedef __attribute__((ext_vector_type(4))) float floatx4;
typedef unsigned short u16;

__device__ __forceinline__ u16 f2bf(float f) {
  union { float f; unsigned u; } c; c.f = f;
  unsigned u = c.u;
  u += 0x7fffu + ((u >> 16) & 1u);   // round-to-nearest-even
  return (u16)(u >> 16);
}
__device__ __forceinline__ u16 f2bf_trunc(float f) {  // cheap: 1 op, ~0.4% err
  union { float f; unsigned u; } c; c.f = f;
  return (u16)(c.u >> 16);
}
__device__ __forceinline__ float fast_exp2(float x) {
#if __has_builtin(__builtin_amdgcn_exp2f)
  return __builtin_amdgcn_exp2f(x);
#else
  return exp2f(x);
#endif
}
__device__ __forceinline__ float fast_rcp(float x) {
#if __has_builtin(__builtin_amdgcn_rcpf)
  return __builtin_amdgcn_rcpf(x);
#else
  return 1.0f / x;
#endif
}
// gelu exact-erf replacement: tanh form via exp2; |err| <~1e-3, clamped safe
__device__ __forceinline__ float gelu_fast(float x) {
  float x2 = x * x;
  float u = x * fmaf(0.10294540f, x2, 2.30211423f);  // = 2*log2e*0.7978846*(x+0.044715x^3)
  u = fminf(fmaxf(u, -30.f), 30.f);
  float t = fast_exp2(u);
  return x * t * fast_rcp(t + 1.0f);                  // x * sigmoid(2v)
}
// async global->LDS, 16B per lane; lds dest = wave-uniform base + lane*16
__device__ __forceinline__ void async16(const u16* g, u16* l) {
  __builtin_amdgcn_global_load_lds(
      (const __attribute__((address_space(1))) unsigned int*)g,
      (__attribute__((address_space(3))) unsigned int*)l, 16, 0, 0);
}
__device__ __forceinline__ short8 load16(const u16* p) {
  return *reinterpret_cast<const short8*>(p);
}

// ---------------- LayerNorm: fp32 in -> bf16 out (one wave per row) ----------
__global__ __launch_bounds__(256) void ln_kernel(const float* __restrict__ x,
                                                 const float* __restrict__ g,
                                                 const float* __restrict__ b,
                                                 u16* __restrict__ out) {
  int row = blockIdx.x * 4 + (threadIdx.x >> 6);
  int lane = threadIdx.x & 63;
  const float* xr = x + (size_t)row * EMB;
  float v[12];
#pragma unroll
  for (int i = 0; i < 3; i++) {
    float4 t = *reinterpret_cast<const float4*>(xr + i * 256 + lane * 4);
    v[i*4+0] = t.x; v[i*4+1] = t.y; v[i*4+2] = t.z; v[i*4+3] = t.w;
  }
  float s = 0.f, ss = 0.f;
#pragma unroll
  for (int i = 0; i < 12; i++) { s += v[i]; ss += v[i] * v[i]; }
#pragma unroll
  for (int off = 1; off < 64; off <<= 1) {
    s  += __shfl_xor(s, off);
    ss += __shfl_xor(ss, off);
  }
  float mu  = s * (1.f / 768.f);
  float var = ss * (1.f / 768.f) - mu * mu;
  float rs  = rsqrtf(var + 1e-5f);
  u16* orow = out + (size_t)row * EMB;
#pragma unroll
  for (int i = 0; i < 3; i++) {
    int col = i * 256 + lane * 4;
    ushort4 o;
    o.x = f2bf((v[i*4+0] - mu) * rs * g[col+0] + b[col+0]);
    o.y = f2bf((v[i*4+1] - mu) * rs * g[col+1] + b[col+1]);
    o.z = f2bf((v[i*4+2] - mu) * rs * g[col+2] + b[col+2]);
    o.w = f2bf((v[i*4+3] - mu) * rs * g[col+3] + b[col+3]);
    *reinterpret_cast<ushort4*>(orow + col) = o;
  }
}

// -------- fused prep: 6 weight transposes (fp32 (K,N) -> bf16 (N,K)) + bias --
// flat grid: [0,2304) Wq/Wk/Wv/Wo (576 each), [2304,4608) W1, [4608,6912) W2,
// [6912,6921) qkv bias concat. threads (32,8).
__global__ void prep_kernel(const float* __restrict__ Wq, const float* __restrict__ Wk,
                            const float* __restrict__ Wv, const float* __restrict__ Wo,
                            const float* __restrict__ W1, const float* __restrict__ W2,
                            u16* __restrict__ wqkv, u16* __restrict__ wot,
                            u16* __restrict__ w1t, u16* __restrict__ w2t,
                            const float* __restrict__ bq, const float* __restrict__ bk,
                            const float* __restrict__ bv, float* __restrict__ obias) {
  __shared__ float t[32][33];
  int id = blockIdx.x;
  int tx = threadIdx.x, ty = threadIdx.y;
  if (id >= 6912) {  // bias concat: 9 blocks x 256 threads
    int i = (id - 6912) * 256 + ty * 32 + tx;
    if (i < QKVD)
      obias[i] = i < EMB ? bq[i] : (i < 2*EMB ? bk[i - EMB] : bv[i - 2*EMB]);
    return;
  }
  const float* in; u16* out; int K, N, bx, by;
  if (id < 2304) {
    int seg = id / 576, rem = id % 576;
    bx = rem % 24; by = rem / 24; K = EMB; N = EMB;
    in = seg == 0 ? Wq : seg == 1 ? Wk : seg == 2 ? Wv : Wo;
    out = seg == 3 ? wot : wqkv + (size_t)seg * EMB * EMB;
  } else if (id < 4608) {
    int rem = id - 2304; bx = rem % 96; by = rem / 96;
    in = W1; out = w1t; K = EMB; N = DFF;
  } else {
    int rem = id - 4608; bx = rem % 24; by = rem / 24;
    in = W2; out = w2t; K = DFF; N = EMB;
  }
  int x0 = bx * 32, y0 = by * 32;
#pragma unroll
  for (int i = 0; i < 4; i++)
    t[ty + i*8][tx] = in[(size_t)(y0 + ty + i*8) * N + x0 + tx];
  __syncthreads();
#pragma unroll
  for (int i = 0; i < 4; i++)
    out[(size_t)(x0 + ty + i*8) * K + y0 + tx] = f2bf(t[tx][ty + i*8]);
}

// -------- V transpose (bf16): qkv (b,l,1536+h*64+d) -> (b,h,d,l) ------------
__global__ void vtrans_kernel(const u16* __restrict__ qkv, u16* __restrict__ vt) {
  __shared__ u16 t[32][33];
  int l0 = blockIdx.x * 32;
  int d0 = blockIdx.y * 32;
  int bh = blockIdx.z;
  int b = bh / HEADS, h = bh % HEADS;
  int tx = threadIdx.x, ty = threadIdx.y;  // 32 x 8
#pragma unroll
  for (int i = 0; i < 4; i++)
    t[ty + i*8][tx] = qkv[(size_t)(b * LSEQ + l0 + ty + i*8) * QKVD + 2*EMB + h * HD + d0 + tx];
  __syncthreads();
#pragma unroll
  for (int i = 0; i < 4; i++)
    vt[(size_t)(bh * HD + d0 + ty + i*8) * LSEQ + l0 + tx] = t[tx][ty + i*8];
}

// -------- GEMM: C = A(MxK,bf16) @ Bt(NxK,bf16)^T + bias, fused epilogue -----
// R1-exact proven config: 128x128, x-fast block order, BK=64,
// global_load_lds 16B staging with XOR-swizzled source columns (chunk (r,c8)
// lives at slot c8^(r&7) -> conflict-free b128 reads). Ordering lever CLOSED
// (R5-R7: XCD %8 / n-fast / stride-8 all ADDED HBM traffic vs x-fast).
// 256^2 4-phase lever CLOSED (R2/R4/R8: 22-26% MfmaUtil; barrier-serialized
// read/MFMA phases cap it; m201-faithful interleave out of budget).
// MFMA operands SWAPPED (bfr, af): C^T layout => lane holds m=l16 and 4
// consecutive n = nbase+lhi*4..+3 in regs -> vectorized bias/res/store.
// mode 0: out bf16 = (acc + bias) * (n<scale_n ? scale : 1)
// mode 1: out fp32 = acc + bias + res
// mode 2: out bf16 = gelu(acc + bias)
#define BK 64
__global__ __launch_bounds__(256) void gemm_kernel(
    const u16* __restrict__ A, const u16* __restrict__ Bt,
    const float* __restrict__ bias, const float* __restrict__ res,
    u16* __restrict__ outb, float* __restrict__ outf,
    int M, int N, int K, int mode, float scale, int scale_n) {
  __shared__ u16 As[128 * BK];
  __shared__ u16 Bs[128 * BK];
  int tid = threadIdx.x;
  int lane = tid & 63, wave = tid >> 6;
  int wm = wave & 1, wn = wave >> 1;        // 2x2 wave grid
  int l16 = lane & 15, lhi = lane >> 4;
  int m0 = blockIdx.x * 128, n0 = blockIdx.y * 128;

  floatx4 acc[4][4];
#pragma unroll
  for (int i = 0; i < 4; i++)
#pragma unroll
    for (int j = 0; j < 4; j++) acc[i][j] = {0.f, 0.f, 0.f, 0.f};

  // ---- staging setup: one async16 covers 8 rows x 8 chunks (1024 B)
  int rr = lane >> 3;                       // row within 8-row group
  int cs = ((lane & 7) ^ rr) * 8;           // swizzled source col (shorts)
  const u16* aptr = A + (size_t)(m0 + wave * 32 + rr) * K + cs;
  const u16* bptr = Bt + (size_t)(n0 + wave * 32 + rr) * K + cs;
  u16* asl = As + (wave * 32) * BK;         // wave-uniform LDS bases
  u16* bsl = Bs + (wave * 32) * BK;

  // ---- read setup: chunk (r,c8) is at r*64 + (c8^(r&7))*8 shorts
  int l7 = l16 & 7;
  int oa0 = (wm * 64 + l16) * BK + ((lhi ^ l7) * 8);     // kk=0: c8=lhi
  int ob0 = (wn * 64 + l16) * BK + ((lhi ^ l7) * 8);
  int oa1 = oa0 ^ 32;                                     // kk=1: c8=lhi^4 -> ^(4*8)
  int ob1 = ob0 ^ 32;

  for (int k0 = 0; k0 < K; k0 += BK) {
    __syncthreads();
#pragma unroll
    for (int i = 0; i < 4; i++) {
      async16(aptr + (size_t)(i * 8) * K + k0, asl + i * 8 * BK);
      async16(bptr + (size_t)(i * 8) * K + k0, bsl + i * 8 * BK);
    }
    __syncthreads();
#pragma unroll
    for (int kk = 0; kk < 2; kk++) {
      int oA = kk ? oa1 : oa0;
      int oB = kk ? ob1 : ob0;
      short8 af[4], bfr[4];
#pragma unroll
      for (int mt = 0; mt < 4; mt++)
        af[mt] = *reinterpret_cast<const short8*>(&As[oA + mt * 16 * BK]);
#pragma unroll
      for (int nt = 0; nt < 4; nt++)
        bfr[nt] = *reinterpret_cast<const short8*>(&Bs[oB + nt * 16 * BK]);
#pragma unroll
      for (int mt = 0; mt < 4; mt++)
#pragma unroll
        for (int nt = 0; nt < 4; nt++)
          acc[mt][nt] = __builtin_amdgcn_mfma_f32_16x16x32_bf16(bfr[nt], af[mt],
                                                                acc[mt][nt], 0, 0, 0);
    }
  }

  // epilogue: lane has row m, cols nbase..nbase+3 in acc[mt][nt][0..3]
#pragma unroll
  for (int mt = 0; mt < 4; mt++) {
    int m = m0 + wm*64 + mt*16 + l16;
#pragma unroll
    for (int nt = 0; nt < 4; nt++) {
      int nbase = n0 + wn*64 + nt*16 + lhi*4;
      float4 bv = *reinterpret_cast<const float4*>(&bias[nbase]);
      float v0 = acc[mt][nt][0] + bv.x, v1 = acc[mt][nt][1] + bv.y;
      float v2 = acc[mt][nt][2] + bv.z, v3 = acc[mt][nt][3] + bv.w;
      if (mode == 1) {
        float4 r = *reinterpret_cast<const float4*>(&res[(size_t)m * N + nbase]);
        float4 o; o.x = v0 + r.x; o.y = v1 + r.y; o.z = v2 + r.z; o.w = v3 + r.w;
        *reinterpret_cast<float4*>(&outf[(size_t)m * N + nbase]) = o;
      } else {
        if (mode == 2) {
          v0 = gelu_fast(v0); v1 = gelu_fast(v1);
          v2 = gelu_fast(v2); v3 = gelu_fast(v3);
        } else {
          float sc = (nbase < scale_n) ? scale : 1.0f;
          v0 *= sc; v1 *= sc; v2 *= sc; v3 *= sc;
        }
        ushort4 o;
        o.x = f2bf(v0); o.y = f2bf(v1); o.z = f2bf(v2); o.w = f2bf(v3);
        *reinterpret_cast<ushort4*>(&outb[(size_t)m * N + nbase]) = o;
      }
    }
  }
}

// -------- Flash attention: LDS-staged K/V + deferred-PV software pipeline ---
// R1 structure (K/V tile staged once per block via global_load_lds, XOR
// source swizzle, dbuf prefetch, one __syncthreads per kt) with ONE change:
// PV(st-1) is deferred until after QK(st)+exp2(st)+write(st). The P
// ds_write -> ds_read round trip was back-to-back (~60-100cyc lgkm stall per
// st, only 3 waves/SIMD to hide it); deferring puts ~200+cyc of QK MFMA +
// exp2 between write(st-1) and read(st-1). Ps[st&1] parity keeps write(st)
// and read(st-1) on opposite buffers; same-wave LDS order handles the
// kt-boundary WAR (write st=0..1 of kt+1 vs tail read of kt).
#define PSTRIDE 76
__global__ __launch_bounds__(256) void flash_kernel(
    const u16* __restrict__ qkv, const u16* __restrict__ vt,
    u16* __restrict__ ctx) {
  __shared__ u16 Kb[2][64 * 64];
  __shared__ u16 Vb[2][64 * 64];
  __shared__ u16 Ps[4][2][16][PSTRIDE];
  int tid = threadIdx.x;
  int lane = tid & 63, w = tid >> 6;
  int l16 = lane & 15, lhi = lane >> 4;

  int i = blockIdx.x;                      // 768 = 4 qb x 192 bh, XCD-affine
  int bh = (i & 7) | ((i >> 5) << 3);      // blocks with equal (i&7, i>>5) share bh
  int qb = (i >> 3) & 3;
  int b = bh / HEADS, h = bh % HEADS;
  int q0 = qb * 256 + w * 64;              // wave's 64 q-rows

  const u16* qbase = qkv + (size_t)(b * LSEQ) * QKVD + h * HD;
  const u16* kbase = qbase + EMB;
  const u16* vbase = vt + (size_t)(bh * HD) * LSEQ;

  // ---- staging setup: wave w covers rows w*16..w*16+15 of each 64-row tile
  int rr = lane >> 3;                       // row within 8-row group
  int c8 = (lane & 7) ^ rr;                 // swizzled source chunk (8 u16)
  const u16* ksrc = kbase + (size_t)(w * 16 + rr) * QKVD + c8 * 8;
  const u16* vsrc = vbase + (size_t)(w * 16 + rr) * LSEQ + c8 * 8;

  // prologue: stage tile 0 into buffer 0
#pragma unroll
  for (int j = 0; j < 2; j++) {
    async16(ksrc + (size_t)(j * 8) * QKVD, &Kb[0][(w * 16 + j * 8) * 64]);
    async16(vsrc + (size_t)(j * 8) * LSEQ, &Vb[0][(w * 16 + j * 8) * 64]);
  }

  // Q^T B-fragments, resident: qf[st][kk] (st = q-subtile of 16)
  short8 qf[4][2];
#pragma unroll
  for (int st = 0; st < 4; st++)
#pragma unroll
    for (int kk = 0; kk < 2; kk++)
      qf[st][kk] = load16(qbase + (size_t)(q0 + st*16 + l16) * QKVD + kk*32 + lhi*8);

  floatx4 o[4][4];                          // o[st][mt]: O^T (d=mt*16+lhi*4+r, q=st*16+l16)
#pragma unroll
  for (int st = 0; st < 4; st++)
#pragma unroll
    for (int mt = 0; mt < 4; mt++) o[st][mt] = {0.f, 0.f, 0.f, 0.f};
  float l_i[4] = {0.f, 0.f, 0.f, 0.f};

  __syncthreads();                          // tile 0 landed (vmcnt drain)

  int cur = 0;
  for (int kt = 0; kt < LSEQ; kt += 64) {
    // stage tile kt+64 into buf[cur^1] (issued early, drained at loop barrier)
    if (kt + 64 < LSEQ) {
      const u16* kn = ksrc + (size_t)(kt + 64) * QKVD;
      const u16* vn = vsrc + (kt + 64);
#pragma unroll
      for (int j = 0; j < 2; j++) {
        async16(kn + (size_t)(j * 8) * QKVD, &Kb[cur ^ 1][(w * 16 + j * 8) * 64]);
        async16(vn + (size_t)(j * 8) * LSEQ, &Vb[cur ^ 1][(w * 16 + j * 8) * 64]);
      }
    }

    // K A-fragments (m=seq, k=d) and V^T A-fragments (m=d, k=seq) from LDS
    short8 kf[4][2], vf[4][2];
#pragma unroll
    for (int mt = 0; mt < 4; mt++) {
      int krow = mt * 16 + l16;             // K: seq-in-tile; V: d
#pragma unroll
      for (int kk = 0; kk < 2; kk++) {
        int slot = ((kk * 4 + lhi) ^ (krow & 7)) * 8;
        kf[mt][kk] = load16(&Kb[cur][krow * 64 + slot]);
        vf[mt][kk] = load16(&Vb[cur][krow * 64 + slot]);
      }
    }

    // software pipeline: QK/exp2/write(st) ... read/PV(st-1)
#pragma unroll
    for (int st = 0; st < 4; st++) {
      u16* pbuf = &Ps[w][st & 1][0][0];
      floatx4 s[4];
#pragma unroll
      for (int mt = 0; mt < 4; mt++) s[mt] = {0.f, 0.f, 0.f, 0.f};
#pragma unroll
      for (int mt = 0; mt < 4; mt++)
#pragma unroll
        for (int kk = 0; kk < 2; kk++)
          s[mt] = __builtin_amdgcn_mfma_f32_16x16x32_bf16(kf[mt][kk], qf[st][kk],
                                                          s[mt], 0, 0, 0);
      // p = exp2(s); lane-local row partial (q = l16 fixed for this lane)
      float ls = 0.f;
#pragma unroll
      for (int mt = 0; mt < 4; mt++) {
        ushort4 pw;
        float p0 = fast_exp2(s[mt][0]), p1 = fast_exp2(s[mt][1]);
        float p2 = fast_exp2(s[mt][2]), p3 = fast_exp2(s[mt][3]);
        ls += (p0 + p1) + (p2 + p3);
        pw.x = f2bf_trunc(p0); pw.y = f2bf_trunc(p1);
        pw.z = f2bf_trunc(p2); pw.w = f2bf_trunc(p3);
        *reinterpret_cast<ushort4*>(&pbuf[l16 * PSTRIDE + mt*16 + lhi*4]) = pw;
      }
      l_i[st] += ls;
      if (st > 0) {                         // deferred PV of previous subtile
        u16* prev = &Ps[w][(st - 1) & 1][0][0];
        short8 pf0 = load16(&prev[l16 * PSTRIDE + 0*32 + lhi*8]);
        short8 pf1 = load16(&prev[l16 * PSTRIDE + 1*32 + lhi*8]);
#pragma unroll
        for (int mt = 0; mt < 4; mt++) {
          o[st-1][mt] = __builtin_amdgcn_mfma_f32_16x16x32_bf16(vf[mt][0], pf0,
                                                                o[st-1][mt], 0, 0, 0);
          o[st-1][mt] = __builtin_amdgcn_mfma_f32_16x16x32_bf16(vf[mt][1], pf1,
                                                                o[st-1][mt], 0, 0, 0);
        }
      }
    }
    {                                       // tail: PV of st=3
      u16* prev = &Ps[w][1][0][0];
      short8 pf0 = load16(&prev[l16 * PSTRIDE + 0*32 + lhi*8]);
      short8 pf1 = load16(&prev[l16 * PSTRIDE + 1*32 + lhi*8]);
#pragma unroll
      for (int mt = 0; mt < 4; mt++) {
        o[3][mt] = __builtin_amdgcn_mfma_f32_16x16x32_bf16(vf[mt][0], pf0,
                                                           o[3][mt], 0, 0, 0);
        o[3][mt] = __builtin_amdgcn_mfma_f32_16x16x32_bf16(vf[mt][1], pf1,
                                                           o[3][mt], 0, 0, 0);
      }
    }

    __syncthreads();                        // buffer rotate + stage drain
    cur ^= 1;
  }

  // reduce row sums across the 4 lhi groups (lanes 16/32/48 apart)
#pragma unroll
  for (int st = 0; st < 4; st++) {
    l_i[st] += __shfl_xor(l_i[st], 16);
    l_i[st] += __shfl_xor(l_i[st], 32);
  }

#pragma unroll
  for (int st = 0; st < 4; st++) {
    float inv = fast_rcp(l_i[st]);
    size_t rowbase = (size_t)(b * LSEQ + q0 + st*16 + l16) * EMB + h * HD;
#pragma unroll
    for (int mt = 0; mt < 4; mt++) {
      ushort4 ow;
      ow.x = f2bf(o[st][mt][0] * inv); ow.y = f2bf(o[st][mt][1] * inv);
      ow.z = f2bf(o[st][mt][2] * inv); ow.w = f2bf(o[st][mt][3] * inv);
      *reinterpret_cast<ushort4*>(&ctx[rowbase + mt*16 + lhi*4]) = ow;
    }
  }
}

extern "C" void kernel_launch(void* const* d_in, const int* in_sizes, int n_in,
                              void* d_out, int out_size, void* d_ws, size_t ws_size,
                              hipStream_t stream) {
  const float* x    = (const float*)d_in[0];
  const float* ln1g = (const float*)d_in[1];
  const float* ln1b = (const float*)d_in[2];
  const float* Wq   = (const float*)d_in[3];
  const float* bq   = (const float*)d_in[4];
  const float* Wk   = (const float*)d_in[5];
  const float* bk   = (const float*)d_in[6];
  const float* Wv   = (const float*)d_in[7];
  const float* bv   = (const float*)d_in[8];
  const float* Wo   = (const float*)d_in[9];
  const float* bo   = (const float*)d_in[10];
  const float* ln2g = (const float*)d_in[11];
  const float* ln2b = (const float*)d_in[12];
  const float* W1   = (const float*)d_in[13];
  const float* b1   = (const float*)d_in[14];
  const float* W2   = (const float*)d_in[15];
  const float* b2   = (const float*)d_in[16];

  char* ws = (char*)d_ws;
  // activations
  u16* qkv_bf = (u16*)(ws);                               // [BL][2304]  75.5 MB
  u16* vt_bf  = (u16*)(ws + (size_t)75497472);            // [192*64][1024] 25.2 MB
  u16* h_bf   = (u16*)(ws + (size_t)100663296);           // [BL][768]   25.2 MB
  float* x2   = (float*)(ws + (size_t)125829120);         // [BL][768]f32 50.3 MB
  u16* m_bf   = (u16*)(ws);                               // [BL][3072] aliases qkv+vt
  // weights (bf16, transposed)
  char* wp = ws + (size_t)176160768;
  u16* wqkv = (u16*)(wp);                                 // [2304][768]
  u16* wot  = (u16*)(wp + (size_t)3538944);
  u16* w1t  = (u16*)(wp + (size_t)3538944 + 1179648);     // [3072][768]
  u16* w2t  = (u16*)(wp + (size_t)3538944 + 1179648 + 4718592); // [768][3072]
  float* qkvbias = (float*)(wp + (size_t)3538944 + 1179648 + 2*4718592);

  dim3 b256(256), tb(32, 8);

  prep_kernel<<<dim3(6921), tb, 0, stream>>>(Wq, Wk, Wv, Wo, W1, W2,
      wqkv, wot, w1t, w2t, bq, bk, bv, qkvbias);

  ln_kernel<<<dim3(BL/4), b256, 0, stream>>>(x, ln1g, ln1b, h_bf);

  // fused QKV: N=2304; q columns get QSCALE folded in (softmax exp2 domain)
  gemm_kernel<<<dim3(128, 18), b256, 0, stream>>>(h_bf, wqkv, qkvbias, nullptr,
      qkv_bf, nullptr, BL, QKVD, EMB, 0, QSCALE, EMB);

  vtrans_kernel<<<dim3(32, 2, BATCH*HEADS), tb, 0, stream>>>(qkv_bf, vt_bf);

  flash_kernel<<<dim3(768), b256, 0, stream>>>(qkv_bf, vt_bf, h_bf);

  gemm_kernel<<<dim3(128, 6), b256, 0, stream>>>(h_bf, wot, bo, x, nullptr, x2,
      BL, EMB, EMB, 1, 1.0f, 0);

  ln_kernel<<<dim3(BL/4), b256, 0, stream>>>(x2, ln2g, ln2b, h_bf);

  gemm_kernel<<<dim3(128, 24), b256, 0, stream>>>(h_bf, w1t, b1, nullptr, m_bf,
      nullptr, BL, DFF, EMB, 2, 1.0f, 0);

  gemm_kernel<<<dim3(128, 6), b256, 0, stream>>>(m_bf, w2t, b2, x2, nullptr,
      (float*)d_out, BL, EMB, DFF, 1, 1.0f, 0);
}

// Round 11
// 542.038 us; speedup vs baseline: 1.1754x; 1.0326x over previous
//
#include <hip/hip_runtime.h>
#include <hip/hip_bf16.h>
#include <math.h>

#define EMB 768
#define DFF 3072
#define HEADS 12
#define HD 64
#define LSEQ 1024
#define BATCH 16
#define BL (BATCH * LSEQ)   // 16384 rows
#define QKVD 2304           // fused q|k|v column dim
#define QSCALE 0.1803368801111204f  // (1/sqrt(64)) * log2(e)

typedef __attribute__((ext_vector_type(8))) short short8;
typedef __attribute__((ext_vector_type(4))) float floatx4;
typedef unsigned short u16;

__device__ __forceinline__ u16 f2bf(float f) {
  union { float f; unsigned u; } c; c.f = f;
  unsigned u = c.u;
  u += 0x7fffu + ((u >> 16) & 1u);   // round-to-nearest-even
  return (u16)(u >> 16);
}
__device__ __forceinline__ u16 f2bf_trunc(float f) {  // cheap: 1 op, ~0.4% err
  union { float f; unsigned u; } c; c.f = f;
  return (u16)(c.u >> 16);
}
__device__ __forceinline__ float fast_exp2(float x) {
#if __has_builtin(__builtin_amdgcn_exp2f)
  return __builtin_amdgcn_exp2f(x);
#else
  return exp2f(x);
#endif
}
__device__ __forceinline__ float fast_rcp(float x) {
#if __has_builtin(__builtin_amdgcn_rcpf)
  return __builtin_amdgcn_rcpf(x);
#else
  return 1.0f / x;
#endif
}
// gelu exact-erf replacement: tanh form via exp2; |err| <~1e-3, clamped safe
__device__ __forceinline__ float gelu_fast(float x) {
  float x2 = x * x;
  float u = x * fmaf(0.10294540f, x2, 2.30211423f);  // = 2*log2e*0.7978846*(x+0.044715x^3)
  u = fminf(fmaxf(u, -30.f), 30.f);
  float t = fast_exp2(u);
  return x * t * fast_rcp(t + 1.0f);                  // x * sigmoid(2v)
}
// async global->LDS, 16B per lane; lds dest = wave-uniform base + lane*16
__device__ __forceinline__ void async16(const u16* g, u16* l) {
  __builtin_amdgcn_global_load_lds(
      (const __attribute__((address_space(1))) unsigned int*)g,
      (__attribute__((address_space(3))) unsigned int*)l, 16, 0, 0);
}
__device__ __forceinline__ short8 load16(const u16* p) {
  return *reinterpret_cast<const short8*>(p);
}

// ---------------- LayerNorm: fp32 in -> bf16 out (one wave per row) ----------
__global__ __launch_bounds__(256) void ln_kernel(const float* __restrict__ x,
                                                 const float* __restrict__ g,
                                                 const float* __restrict__ b,
                                                 u16* __restrict__ out) {
  int row = blockIdx.x * 4 + (threadIdx.x >> 6);
  int lane = threadIdx.x & 63;
  const float* xr = x + (size_t)row * EMB;
  float v[12];
#pragma unroll
  for (int i = 0; i < 3; i++) {
    float4 t = *reinterpret_cast<const float4*>(xr + i * 256 + lane * 4);
    v[i*4+0] = t.x; v[i*4+1] = t.y; v[i*4+2] = t.z; v[i*4+3] = t.w;
  }
  float s = 0.f, ss = 0.f;
#pragma unroll
  for (int i = 0; i < 12; i++) { s += v[i]; ss += v[i] * v[i]; }
#pragma unroll
  for (int off = 1; off < 64; off <<= 1) {
    s  += __shfl_xor(s, off);
    ss += __shfl_xor(ss, off);
  }
  float mu  = s * (1.f / 768.f);
  float var = ss * (1.f / 768.f) - mu * mu;
  float rs  = rsqrtf(var + 1e-5f);
  u16* orow = out + (size_t)row * EMB;
#pragma unroll
  for (int i = 0; i < 3; i++) {
    int col = i * 256 + lane * 4;
    ushort4 o;
    o.x = f2bf((v[i*4+0] - mu) * rs * g[col+0] + b[col+0]);
    o.y = f2bf((v[i*4+1] - mu) * rs * g[col+1] + b[col+1]);
    o.z = f2bf((v[i*4+2] - mu) * rs * g[col+2] + b[col+2]);
    o.w = f2bf((v[i*4+3] - mu) * rs * g[col+3] + b[col+3]);
    *reinterpret_cast<ushort4*>(orow + col) = o;
  }
}

// -------- fused prep: 6 weight transposes (fp32 (K,N) -> bf16 (N,K)) + bias --
// flat grid: [0,2304) Wq/Wk/Wv/Wo (576 each), [2304,4608) W1, [4608,6912) W2,
// [6912,6921) qkv bias concat. threads (32,8).
__global__ void prep_kernel(const float* __restrict__ Wq, const float* __restrict__ Wk,
                            const float* __restrict__ Wv, const float* __restrict__ Wo,
                            const float* __restrict__ W1, const float* __restrict__ W2,
                            u16* __restrict__ wqkv, u16* __restrict__ wot,
                            u16* __restrict__ w1t, u16* __restrict__ w2t,
                            const float* __restrict__ bq, const float* __restrict__ bk,
                            const float* __restrict__ bv, float* __restrict__ obias) {
  __shared__ float t[32][33];
  int id = blockIdx.x;
  int tx = threadIdx.x, ty = threadIdx.y;
  if (id >= 6912) {  // bias concat: 9 blocks x 256 threads
    int i = (id - 6912) * 256 + ty * 32 + tx;
    if (i < QKVD)
      obias[i] = i < EMB ? bq[i] : (i < 2*EMB ? bk[i - EMB] : bv[i - 2*EMB]);
    return;
  }
  const float* in; u16* out; int K, N, bx, by;
  if (id < 2304) {
    int seg = id / 576, rem = id % 576;
    bx = rem % 24; by = rem / 24; K = EMB; N = EMB;
    in = seg == 0 ? Wq : seg == 1 ? Wk : seg == 2 ? Wv : Wo;
    out = seg == 3 ? wot : wqkv + (size_t)seg * EMB * EMB;
  } else if (id < 4608) {
    int rem = id - 2304; bx = rem % 96; by = rem / 96;
    in = W1; out = w1t; K = EMB; N = DFF;
  } else {
    int rem = id - 4608; bx = rem % 24; by = rem / 24;
    in = W2; out = w2t; K = DFF; N = EMB;
  }
  int x0 = bx * 32, y0 = by * 32;
#pragma unroll
  for (int i = 0; i < 4; i++)
    t[ty + i*8][tx] = in[(size_t)(y0 + ty + i*8) * N + x0 + tx];
  __syncthreads();
#pragma unroll
  for (int i = 0; i < 4; i++)
    out[(size_t)(x0 + ty + i*8) * K + y0 + tx] = f2bf(t[tx][ty + i*8]);
}

// -------- V transpose (bf16): qkv (b,l,1536+h*64+d) -> (b,h,d,l) ------------
__global__ void vtrans_kernel(const u16* __restrict__ qkv, u16* __restrict__ vt) {
  __shared__ u16 t[32][33];
  int l0 = blockIdx.x * 32;
  int d0 = blockIdx.y * 32;
  int bh = blockIdx.z;
  int b = bh / HEADS, h = bh % HEADS;
  int tx = threadIdx.x, ty = threadIdx.y;  // 32 x 8
#pragma unroll
  for (int i = 0; i < 4; i++)
    t[ty + i*8][tx] = qkv[(size_t)(b * LSEQ + l0 + ty + i*8) * QKVD + 2*EMB + h * HD + d0 + tx];
  __syncthreads();
#pragma unroll
  for (int i = 0; i < 4; i++)
    vt[(size_t)(bh * HD + d0 + ty + i*8) * LSEQ + l0 + tx] = t[tx][ty + i*8];
}

// -------- GEMM: C = A(MxK,bf16) @ Bt(NxK,bf16)^T + bias, fused epilogue -----
// R1-exact proven config: 128x128, x-fast block order, BK=64,
// global_load_lds 16B staging with XOR-swizzled source columns (chunk (r,c8)
// lives at slot c8^(r&7) -> conflict-free b128 reads). Ordering lever CLOSED
// (R5-R7: XCD %8 / n-fast / stride-8 all ADDED HBM traffic vs x-fast).
// 256^2 4-phase lever CLOSED (R2/R4/R8: 22-26% MfmaUtil; barrier-serialized
// read/MFMA phases cap it; m201-faithful interleave out of budget).
// MFMA operands SWAPPED (bfr, af): C^T layout => lane holds m=l16 and 4
// consecutive n = nbase+lhi*4..+3 in regs -> vectorized bias/res/store.
// mode 0: out bf16 = (acc + bias) * (n<scale_n ? scale : 1)
// mode 1: out fp32 = acc + bias + res
// mode 2: out bf16 = gelu(acc + bias)
#define BK 64
__global__ __launch_bounds__(256) void gemm_kernel(
    const u16* __restrict__ A, const u16* __restrict__ Bt,
    const float* __restrict__ bias, const float* __restrict__ res,
    u16* __restrict__ outb, float* __restrict__ outf,
    int M, int N, int K, int mode, float scale, int scale_n) {
  __shared__ u16 As[128 * BK];
  __shared__ u16 Bs[128 * BK];
  int tid = threadIdx.x;
  int lane = tid & 63, wave = tid >> 6;
  int wm = wave & 1, wn = wave >> 1;        // 2x2 wave grid
  int l16 = lane & 15, lhi = lane >> 4;
  int m0 = blockIdx.x * 128, n0 = blockIdx.y * 128;

  floatx4 acc[4][4];
#pragma unroll
  for (int i = 0; i < 4; i++)
#pragma unroll
    for (int j = 0; j < 4; j++) acc[i][j] = {0.f, 0.f, 0.f, 0.f};

  // ---- staging setup: one async16 covers 8 rows x 8 chunks (1024 B)
  int rr = lane >> 3;                       // row within 8-row group
  int cs = ((lane & 7) ^ rr) * 8;           // swizzled source col (shorts)
  const u16* aptr = A + (size_t)(m0 + wave * 32 + rr) * K + cs;
  const u16* bptr = Bt + (size_t)(n0 + wave * 32 + rr) * K + cs;
  u16* asl = As + (wave * 32) * BK;         // wave-uniform LDS bases
  u16* bsl = Bs + (wave * 32) * BK;

  // ---- read setup: chunk (r,c8) is at r*64 + (c8^(r&7))*8 shorts
  int l7 = l16 & 7;
  int oa0 = (wm * 64 + l16) * BK + ((lhi ^ l7) * 8);     // kk=0: c8=lhi
  int ob0 = (wn * 64 + l16) * BK + ((lhi ^ l7) * 8);
  int oa1 = oa0 ^ 32;                                     // kk=1: c8=lhi^4 -> ^(4*8)
  int ob1 = ob0 ^ 32;

  for (int k0 = 0; k0 < K; k0 += BK) {
    __syncthreads();
#pragma unroll
    for (int i = 0; i < 4; i++) {
      async16(aptr + (size_t)(i * 8) * K + k0, asl + i * 8 * BK);
      async16(bptr + (size_t)(i * 8) * K + k0, bsl + i * 8 * BK);
    }
    __syncthreads();
#pragma unroll
    for (int kk = 0; kk < 2; kk++) {
      int oA = kk ? oa1 : oa0;
      int oB = kk ? ob1 : ob0;
      short8 af[4], bfr[4];
#pragma unroll
      for (int mt = 0; mt < 4; mt++)
        af[mt] = *reinterpret_cast<const short8*>(&As[oA + mt * 16 * BK]);
#pragma unroll
      for (int nt = 0; nt < 4; nt++)
        bfr[nt] = *reinterpret_cast<const short8*>(&Bs[oB + nt * 16 * BK]);
#pragma unroll
      for (int mt = 0; mt < 4; mt++)
#pragma unroll
        for (int nt = 0; nt < 4; nt++)
          acc[mt][nt] = __builtin_amdgcn_mfma_f32_16x16x32_bf16(bfr[nt], af[mt],
                                                                acc[mt][nt], 0, 0, 0);
    }
  }

  // epilogue: lane has row m, cols nbase..nbase+3 in acc[mt][nt][0..3]
#pragma unroll
  for (int mt = 0; mt < 4; mt++) {
    int m = m0 + wm*64 + mt*16 + l16;
#pragma unroll
    for (int nt = 0; nt < 4; nt++) {
      int nbase = n0 + wn*64 + nt*16 + lhi*4;
      float4 bv = *reinterpret_cast<const float4*>(&bias[nbase]);
      float v0 = acc[mt][nt][0] + bv.x, v1 = acc[mt][nt][1] + bv.y;
      float v2 = acc[mt][nt][2] + bv.z, v3 = acc[mt][nt][3] + bv.w;
      if (mode == 1) {
        float4 r = *reinterpret_cast<const float4*>(&res[(size_t)m * N + nbase]);
        float4 o; o.x = v0 + r.x; o.y = v1 + r.y; o.z = v2 + r.z; o.w = v3 + r.w;
        *reinterpret_cast<float4*>(&outf[(size_t)m * N + nbase]) = o;
      } else {
        if (mode == 2) {
          v0 = gelu_fast(v0); v1 = gelu_fast(v1);
          v2 = gelu_fast(v2); v3 = gelu_fast(v3);
        } else {
          float sc = (nbase < scale_n) ? scale : 1.0f;
          v0 *= sc; v1 *= sc; v2 *= sc; v3 *= sc;
        }
        ushort4 o;
        o.x = f2bf(v0); o.y = f2bf(v1); o.z = f2bf(v2); o.w = f2bf(v3);
        *reinterpret_cast<ushort4*>(&outb[(size_t)m * N + nbase]) = o;
      }
    }
  }
}

// -------- Flash attention: LDS-staged K/V + 2-stage deferred-PV pipeline ----
// R10 (+6us win) deferred PV(st-1) behind QK/exp2/write(st). This round
// extends the same mechanism across the kt boundary: PV(st=3) of tile t runs
// at the TOP of tile t+1 (V frags kept in vfp regs, +32 VGPR = same
// occupancy bracket), with its 2 Ps reads issued BEFORE the 16 kf/vf
// ds_reads so its lgkmcnt wait is minimal and the 8 PV MFMAs overlap the
// kf/vf load latency. Hazards: Ps[w] is per-wave; read(PV3 of t) precedes
// write(st=1 of t+1, same parity buffer) in same-wave program order ->
// in-order LDS is safe. vfp is registers -> barrier-immune. Final tile's
// PV(3) peeled after the loop.
#define PSTRIDE 76
__global__ __launch_bounds__(256) void flash_kernel(
    const u16* __restrict__ qkv, const u16* __restrict__ vt,
    u16* __restrict__ ctx) {
  __shared__ u16 Kb[2][64 * 64];
  __shared__ u16 Vb[2][64 * 64];
  __shared__ u16 Ps[4][2][16][PSTRIDE];
  int tid = threadIdx.x;
  int lane = tid & 63, w = tid >> 6;
  int l16 = lane & 15, lhi = lane >> 4;

  int i = blockIdx.x;                      // 768 = 4 qb x 192 bh, XCD-affine
  int bh = (i & 7) | ((i >> 5) << 3);      // blocks with equal (i&7, i>>5) share bh
  int qb = (i >> 3) & 3;
  int b = bh / HEADS, h = bh % HEADS;
  int q0 = qb * 256 + w * 64;              // wave's 64 q-rows

  const u16* qbase = qkv + (size_t)(b * LSEQ) * QKVD + h * HD;
  const u16* kbase = qbase + EMB;
  const u16* vbase = vt + (size_t)(bh * HD) * LSEQ;

  // ---- staging setup: wave w covers rows w*16..w*16+15 of each 64-row tile
  int rr = lane >> 3;                       // row within 8-row group
  int c8 = (lane & 7) ^ rr;                 // swizzled source chunk (8 u16)
  const u16* ksrc = kbase + (size_t)(w * 16 + rr) * QKVD + c8 * 8;
  const u16* vsrc = vbase + (size_t)(w * 16 + rr) * LSEQ + c8 * 8;

  // prologue: stage tile 0 into buffer 0
#pragma unroll
  for (int j = 0; j < 2; j++) {
    async16(ksrc + (size_t)(j * 8) * QKVD, &Kb[0][(w * 16 + j * 8) * 64]);
    async16(vsrc + (size_t)(j * 8) * LSEQ, &Vb[0][(w * 16 + j * 8) * 64]);
  }

  // Q^T B-fragments, resident: qf[st][kk] (st = q-subtile of 16)
  short8 qf[4][2];
#pragma unroll
  for (int st = 0; st < 4; st++)
#pragma unroll
    for (int kk = 0; kk < 2; kk++)
      qf[st][kk] = load16(qbase + (size_t)(q0 + st*16 + l16) * QKVD + kk*32 + lhi*8);

  floatx4 o[4][4];                          // o[st][mt]: O^T (d=mt*16+lhi*4+r, q=st*16+l16)
#pragma unroll
  for (int st = 0; st < 4; st++)
#pragma unroll
    for (int mt = 0; mt < 4; mt++) o[st][mt] = {0.f, 0.f, 0.f, 0.f};
  float l_i[4] = {0.f, 0.f, 0.f, 0.f};

  short8 vfp[4][2];                         // prev tile's V frags (PV3 deferral)

  __syncthreads();                          // tile 0 landed (vmcnt drain)

  int cur = 0;
  for (int kt = 0; kt < LSEQ; kt += 64) {
    // stage tile kt+64 into buf[cur^1] (issued early, drained at loop barrier)
    if (kt + 64 < LSEQ) {
      const u16* kn = ksrc + (size_t)(kt + 64) * QKVD;
      const u16* vn = vsrc + (kt + 64);
#pragma unroll
      for (int j = 0; j < 2; j++) {
        async16(kn + (size_t)(j * 8) * QKVD, &Kb[cur ^ 1][(w * 16 + j * 8) * 64]);
        async16(vn + (size_t)(j * 8) * LSEQ, &Vb[cur ^ 1][(w * 16 + j * 8) * 64]);
      }
    }

    // cross-boundary deferred PV(st=3) of previous tile: pf reads issued
    // first (minimal lgkmcnt wait), MFMAs overlap the kf/vf reads below.
    if (kt > 0) {
      u16* prev = &Ps[w][1][0][0];
      short8 pf0 = load16(&prev[l16 * PSTRIDE + 0*32 + lhi*8]);
      short8 pf1 = load16(&prev[l16 * PSTRIDE + 1*32 + lhi*8]);
#pragma unroll
      for (int mt = 0; mt < 4; mt++) {
        o[3][mt] = __builtin_amdgcn_mfma_f32_16x16x32_bf16(vfp[mt][0], pf0,
                                                           o[3][mt], 0, 0, 0);
        o[3][mt] = __builtin_amdgcn_mfma_f32_16x16x32_bf16(vfp[mt][1], pf1,
                                                           o[3][mt], 0, 0, 0);
      }
    }

    // K A-fragments (m=seq, k=d) and V^T A-fragments (m=d, k=seq) from LDS
    short8 kf[4][2], vf[4][2];
#pragma unroll
    for (int mt = 0; mt < 4; mt++) {
      int krow = mt * 16 + l16;             // K: seq-in-tile; V: d
#pragma unroll
      for (int kk = 0; kk < 2; kk++) {
        int slot = ((kk * 4 + lhi) ^ (krow & 7)) * 8;
        kf[mt][kk] = load16(&Kb[cur][krow * 64 + slot]);
        vf[mt][kk] = load16(&Vb[cur][krow * 64 + slot]);
      }
    }

    // software pipeline: QK/exp2/write(st) ... read/PV(st-1)
#pragma unroll
    for (int st = 0; st < 4; st++) {
      u16* pbuf = &Ps[w][st & 1][0][0];
      floatx4 s[4];
#pragma unroll
      for (int mt = 0; mt < 4; mt++) s[mt] = {0.f, 0.f, 0.f, 0.f};
#pragma unroll
      for (int mt = 0; mt < 4; mt++)
#pragma unroll
        for (int kk = 0; kk < 2; kk++)
          s[mt] = __builtin_amdgcn_mfma_f32_16x16x32_bf16(kf[mt][kk], qf[st][kk],
                                                          s[mt], 0, 0, 0);
      // p = exp2(s); lane-local row partial (q = l16 fixed for this lane)
      float ls = 0.f;
#pragma unroll
      for (int mt = 0; mt < 4; mt++) {
        ushort4 pw;
        float p0 = fast_exp2(s[mt][0]), p1 = fast_exp2(s[mt][1]);
        float p2 = fast_exp2(s[mt][2]), p3 = fast_exp2(s[mt][3]);
        ls += (p0 + p1) + (p2 + p3);
        pw.x = f2bf_trunc(p0); pw.y = f2bf_trunc(p1);
        pw.z = f2bf_trunc(p2); pw.w = f2bf_trunc(p3);
        *reinterpret_cast<ushort4*>(&pbuf[l16 * PSTRIDE + mt*16 + lhi*4]) = pw;
      }
      l_i[st] += ls;
      if (st > 0) {                         // deferred PV of previous subtile
        u16* prev = &Ps[w][(st - 1) & 1][0][0];
        short8 pf0 = load16(&prev[l16 * PSTRIDE + 0*32 + lhi*8]);
        short8 pf1 = load16(&prev[l16 * PSTRIDE + 1*32 + lhi*8]);
#pragma unroll
        for (int mt = 0; mt < 4; mt++) {
          o[st-1][mt] = __builtin_amdgcn_mfma_f32_16x16x32_bf16(vf[mt][0], pf0,
                                                                o[st-1][mt], 0, 0, 0);
          o[st-1][mt] = __builtin_amdgcn_mfma_f32_16x16x32_bf16(vf[mt][1], pf1,
                                                                o[st-1][mt], 0, 0, 0);
        }
      }
    }

    // keep this tile's V frags for the cross-boundary PV(3)
#pragma unroll
    for (int mt = 0; mt < 4; mt++) {
      vfp[mt][0] = vf[mt][0];
      vfp[mt][1] = vf[mt][1];
    }

    __syncthreads();                        // buffer rotate + stage drain
    cur ^= 1;
  }

  {                                         // peeled PV(3) of the last tile
    u16* prev = &Ps[w][1][0][0];
    short8 pf0 = load16(&prev[l16 * PSTRIDE + 0*32 + lhi*8]);
    short8 pf1 = load16(&prev[l16 * PSTRIDE + 1*32 + lhi*8]);
#pragma unroll
    for (int mt = 0; mt < 4; mt++) {
      o[3][mt] = __builtin_amdgcn_mfma_f32_16x16x32_bf16(vfp[mt][0], pf0,
                                                         o[3][mt], 0, 0, 0);
      o[3][mt] = __builtin_amdgcn_mfma_f32_16x16x32_bf16(vfp[mt][1], pf1,
                                                         o[3][mt], 0, 0, 0);
    }
  }

  // reduce row sums across the 4 lhi groups (lanes 16/32/48 apart)
#pragma unroll
  for (int st = 0; st < 4; st++) {
    l_i[st] += __shfl_xor(l_i[st], 16);
    l_i[st] += __shfl_xor(l_i[st], 32);
  }

#pragma unroll
  for (int st = 0; st < 4; st++) {
    float inv = fast_rcp(l_i[st]);
    size_t rowbase = (size_t)(b * LSEQ + q0 + st*16 + l16) * EMB + h * HD;
#pragma unroll
    for (int mt = 0; mt < 4; mt++) {
      ushort4 ow;
      ow.x = f2bf(o[st][mt][0] * inv); ow.y = f2bf(o[st][mt][1] * inv);
      ow.z = f2bf(o[st][mt][2] * inv); ow.w = f2bf(o[st][mt][3] * inv);
      *reinterpret_cast<ushort4*>(&ctx[rowbase + mt*16 + lhi*4]) = ow;
    }
  }
}

extern "C" void kernel_launch(void* const* d_in, const int* in_sizes, int n_in,
                              void* d_out, int out_size, void* d_ws, size_t ws_size,
                              hipStream_t stream) {
  const float* x    = (const float*)d_in[0];
  const float* ln1g = (const float*)d_in[1];
  const float* ln1b = (const float*)d_in[2];
  const float* Wq   = (const float*)d_in[3];
  const float* bq   = (const float*)d_in[4];
  const float* Wk   = (const float*)d_in[5];
  const float* bk   = (const float*)d_in[6];
  const float* Wv   = (const float*)d_in[7];
  const float* bv   = (const float*)d_in[8];
  const float* Wo   = (const float*)d_in[9];
  const float* bo   = (const float*)d_in[10];
  const float* ln2g = (const float*)d_in[11];
  const float* ln2b = (const float*)d_in[12];
  const float* W1   = (const float*)d_in[13];
  const float* b1   = (const float*)d_in[14];
  const float* W2   = (const float*)d_in[15];
  const float* b2   = (const float*)d_in[16];

  char* ws = (char*)d_ws;
  // activations
  u16* qkv_bf = (u16*)(ws);                               // [BL][2304]  75.5 MB
  u16* vt_bf  = (u16*)(ws + (size_t)75497472);            // [192*64][1024] 25.2 MB
  u16* h_bf   = (u16*)(ws + (size_t)100663296);           // [BL][768]   25.2 MB
  float* x2   = (float*)(ws + (size_t)125829120);         // [BL][768]f32 50.3 MB
  u16* m_bf   = (u16*)(ws);                               // [BL][3072] aliases qkv+vt
  // weights (bf16, transposed)
  char* wp = ws + (size_t)176160768;
  u16* wqkv = (u16*)(wp);                                 // [2304][768]
  u16* wot  = (u16*)(wp + (size_t)3538944);
  u16* w1t  = (u16*)(wp + (size_t)3538944 + 1179648);     // [3072][768]
  u16* w2t  = (u16*)(wp + (size_t)3538944 + 1179648 + 4718592); // [768][3072]
  float* qkvbias = (float*)(wp + (size_t)3538944 + 1179648 + 2*4718592);

  dim3 b256(256), tb(32, 8);

  prep_kernel<<<dim3(6921), tb, 0, stream>>>(Wq, Wk, Wv, Wo, W1, W2,
      wqkv, wot, w1t, w2t, bq, bk, bv, qkvbias);

  ln_kernel<<<dim3(BL/4), b256, 0, stream>>>(x, ln1g, ln1b, h_bf);

  // fused QKV: N=2304; q columns get QSCALE folded in (softmax exp2 domain)
  gemm_kernel<<<dim3(128, 18), b256, 0, stream>>>(h_bf, wqkv, qkvbias, nullptr,
      qkv_bf, nullptr, BL, QKVD, EMB, 0, QSCALE, EMB);

  vtrans_kernel<<<dim3(32, 2, BATCH*HEADS), tb, 0, stream>>>(qkv_bf, vt_bf);

  flash_kernel<<<dim3(768), b256, 0, stream>>>(qkv_bf, vt_bf, h_bf);

  gemm_kernel<<<dim3(128, 6), b256, 0, stream>>>(h_bf, wot, bo, x, nullptr, x2,
      BL, EMB, EMB, 1, 1.0f, 0);

  ln_kernel<<<dim3(BL/4), b256, 0, stream>>>(x2, ln2g, ln2b, h_bf);

  gemm_kernel<<<dim3(128, 24), b256, 0, stream>>>(h_bf, w1t, b1, nullptr, m_bf,
      nullptr, BL, DFF, EMB, 2, 1.0f, 0);

  gemm_kernel<<<dim3(128, 6), b256, 0, stream>>>(m_bf, w2t, b2, x2, nullptr,
      (float*)d_out, BL, EMB, DFF, 1, 1.0f, 0);
}